// Round 1
// baseline (3939.367 us; speedup 1.0000x reference)
//
#include <hip/hip_runtime.h>
#include <hip/hip_bf16.h>
#include <math.h>

#define Bdim 2
#define Sdim 4096
#define Hdim 1024
#define Edim 8
#define Ddim 2048
#define Tdim (Bdim*Sdim)   // 8192 tokens

#define TM 64
#define TN 64
#define TK 32

// ---------------- Router: one wave (64 lanes) per token ----------------
__global__ __launch_bounds__(256) void router_kernel(
    const float* __restrict__ x, const float* __restrict__ gw,
    int* __restrict__ cnt, float* __restrict__ psum,
    int* __restrict__ ltok, float* __restrict__ lw)
{
    int wave = threadIdx.x >> 6;
    int lane = threadIdx.x & 63;
    int t = blockIdx.x * 4 + wave;
    if (t >= Tdim) return;

    double acc[Edim];
#pragma unroll
    for (int e = 0; e < Edim; ++e) acc[e] = 0.0;

    for (int i = 0; i < Hdim / 64; ++i) {
        double xv = (double)x[(size_t)t * Hdim + i * 64 + lane];
#pragma unroll
        for (int e = 0; e < Edim; ++e)
            acc[e] += xv * (double)gw[e * Hdim + i * 64 + lane];
    }
#pragma unroll
    for (int e = 0; e < Edim; ++e) {
        double v = acc[e];
        for (int off = 32; off > 0; off >>= 1)
            v += __shfl_down(v, off, 64);
        acc[e] = v;  // valid on lane 0
    }
    if (lane == 0) {
        double m = acc[0];
#pragma unroll
        for (int e = 1; e < Edim; ++e) m = fmax(m, acc[e]);
        double ex[Edim], s = 0.0;
#pragma unroll
        for (int e = 0; e < Edim; ++e) { ex[e] = exp(acc[e] - m); s += ex[e]; }
        for (int e = 0; e < Edim; ++e)
            atomicAdd(&psum[e], (float)(ex[e] / s));
        // top-2 on logits (== top-2 on probs); ties -> lower index (jax semantics)
        int e1 = 0;
        for (int e = 1; e < Edim; ++e) if (acc[e] > acc[e1]) e1 = e;
        int e2 = -1;
        for (int e = 0; e < Edim; ++e) {
            if (e == e1) continue;
            if (e2 < 0 || acc[e] > acc[e2]) e2 = e;
        }
        double p1 = ex[e1], p2 = ex[e2];
        double inv = 1.0 / (p1 + p2);
        int pos1 = atomicAdd(&cnt[e1], 1);
        ltok[e1 * Tdim + pos1] = t;  lw[e1 * Tdim + pos1] = (float)(p1 * inv);
        int pos2 = atomicAdd(&cnt[e2], 1);
        ltok[e2 * Tdim + pos2] = t;  lw[e2 * Tdim + pos2] = (float)(p2 * inv);
    }
}

// ---------------- Aux loss ----------------
__global__ void aux_kernel(const int* __restrict__ cnt,
                           const float* __restrict__ psum,
                           float* __restrict__ out_aux)
{
    if (threadIdx.x == 0 && blockIdx.x == 0) {
        double s = 0.0;
        for (int e = 0; e < Edim; ++e)
            s += ((double)cnt[e] / (double)Bdim) * ((double)psum[e] / (double)Tdim);
        out_aux[0] = (float)((double)Edim * s);
    }
}

// ---------------- GEMM1: hid = gelu(X[list] @ w1_e + b1_e) ----------------
__global__ __launch_bounds__(256) void gemm1_kernel(
    const float* __restrict__ x, const float* __restrict__ w1,
    const float* __restrict__ b1, const int* __restrict__ cnt,
    const int* __restrict__ ltok, float* __restrict__ hid,
    int e, int row_base)
{
    int n_e = cnt[e];
    int rowt0 = row_base + blockIdx.y * TM;
    if (rowt0 >= n_e) return;
    int col0 = blockIdx.x * TN;

    __shared__ float As[TM][TK + 4];
    __shared__ float Bs[TK][TN];

    int tid = threadIdx.x;
    int tx = tid & 15, ty = tid >> 4;

    float acc[4][4];
#pragma unroll
    for (int i = 0; i < 4; ++i)
#pragma unroll
        for (int j = 0; j < 4; ++j) acc[i][j] = 0.f;

    int am[2], ak[2], atok[2], bk[2], bn[2];
#pragma unroll
    for (int i = 0; i < 2; ++i) {
        int e4 = tid + i * 256;
        am[i] = e4 >> 3; ak[i] = (e4 & 7) * 4;
        int gr = rowt0 + am[i];
        atok[i] = (gr < n_e) ? ltok[e * Tdim + gr] : 0;
        bk[i] = e4 >> 4; bn[i] = (e4 & 15) * 4;
    }
    const float* wB = w1 + (size_t)e * Hdim * Ddim;

    for (int k0 = 0; k0 < Hdim; k0 += TK) {
#pragma unroll
        for (int i = 0; i < 2; ++i) {
            float4 v = *(const float4*)(x + (size_t)atok[i] * Hdim + k0 + ak[i]);
            *(float4*)(&As[am[i]][ak[i]]) = v;
            float4 w = *(const float4*)(wB + (size_t)(k0 + bk[i]) * Ddim + col0 + bn[i]);
            *(float4*)(&Bs[bk[i]][bn[i]]) = w;
        }
        __syncthreads();
#pragma unroll
        for (int kk = 0; kk < TK; kk += 4) {
            float4 a4[4], b4[4];
#pragma unroll
            for (int i = 0; i < 4; ++i) a4[i] = *(const float4*)(&As[ty * 4 + i][kk]);
#pragma unroll
            for (int j = 0; j < 4; ++j) b4[j] = *(const float4*)(&Bs[kk + j][tx * 4]);
#pragma unroll
            for (int i = 0; i < 4; ++i) {
                const float* ai = (const float*)&a4[i];
#pragma unroll
                for (int j = 0; j < 4; ++j) {
                    acc[i][0] += ai[j] * b4[j].x;
                    acc[i][1] += ai[j] * b4[j].y;
                    acc[i][2] += ai[j] * b4[j].z;
                    acc[i][3] += ai[j] * b4[j].w;
                }
            }
        }
        __syncthreads();
    }

    int lrow0 = rowt0 - row_base;
#pragma unroll
    for (int i = 0; i < 4; ++i) {
        int gr = rowt0 + ty * 4 + i;
        if (gr >= n_e) continue;
        int lr = lrow0 + ty * 4 + i;
#pragma unroll
        for (int j = 0; j < 4; ++j) {
            int cc = col0 + tx * 4 + j;
            float v = acc[i][j] + b1[e * Ddim + cc];
            float g = 0.5f * v * (1.0f + erff(v * 0.70710678118654752440f));
            hid[(size_t)lr * Ddim + cc] = g;
        }
    }
}

// ---------------- GEMM2: out[tok] += p * (hid @ w2_e + b2_e) ----------------
__global__ __launch_bounds__(256) void gemm2_kernel(
    const float* __restrict__ hid, const float* __restrict__ w2,
    const float* __restrict__ b2, const int* __restrict__ cnt,
    const int* __restrict__ ltok, const float* __restrict__ lw,
    float* __restrict__ out, int e, int row_base)
{
    int n_e = cnt[e];
    int rowt0 = row_base + blockIdx.y * TM;
    if (rowt0 >= n_e) return;
    int col0 = blockIdx.x * TN;

    __shared__ float As[TM][TK + 4];
    __shared__ float Bs[TK][TN];

    int tid = threadIdx.x;
    int tx = tid & 15, ty = tid >> 4;

    float acc[4][4];
#pragma unroll
    for (int i = 0; i < 4; ++i)
#pragma unroll
        for (int j = 0; j < 4; ++j) acc[i][j] = 0.f;

    int am[2], ak[2], bk[2], bn[2];
#pragma unroll
    for (int i = 0; i < 2; ++i) {
        int e4 = tid + i * 256;
        am[i] = e4 >> 3; ak[i] = (e4 & 7) * 4;
        bk[i] = e4 >> 4; bn[i] = (e4 & 15) * 4;
    }
    int lrow0 = rowt0 - row_base;
    const float* wB = w2 + (size_t)e * Ddim * Hdim;

    for (int k0 = 0; k0 < Ddim; k0 += TK) {
#pragma unroll
        for (int i = 0; i < 2; ++i) {
            float4 v = *(const float4*)(hid + (size_t)(lrow0 + am[i]) * Ddim + k0 + ak[i]);
            *(float4*)(&As[am[i]][ak[i]]) = v;
            float4 w = *(const float4*)(wB + (size_t)(k0 + bk[i]) * Hdim + col0 + bn[i]);
            *(float4*)(&Bs[bk[i]][bn[i]]) = w;
        }
        __syncthreads();
#pragma unroll
        for (int kk = 0; kk < TK; kk += 4) {
            float4 a4[4], b4[4];
#pragma unroll
            for (int i = 0; i < 4; ++i) a4[i] = *(const float4*)(&As[ty * 4 + i][kk]);
#pragma unroll
            for (int j = 0; j < 4; ++j) b4[j] = *(const float4*)(&Bs[kk + j][tx * 4]);
#pragma unroll
            for (int i = 0; i < 4; ++i) {
                const float* ai = (const float*)&a4[i];
#pragma unroll
                for (int j = 0; j < 4; ++j) {
                    acc[i][0] += ai[j] * b4[j].x;
                    acc[i][1] += ai[j] * b4[j].y;
                    acc[i][2] += ai[j] * b4[j].z;
                    acc[i][3] += ai[j] * b4[j].w;
                }
            }
        }
        __syncthreads();
    }

#pragma unroll
    for (int i = 0; i < 4; ++i) {
        int gr = rowt0 + ty * 4 + i;
        if (gr >= n_e) continue;
        int tok = ltok[e * Tdim + gr];
        float p = lw[e * Tdim + gr];
#pragma unroll
        for (int j = 0; j < 4; ++j) {
            int cc = col0 + tx * 4 + j;
            float v = p * (acc[i][j] + b2[e * Hdim + cc]);
            atomicAdd(&out[(size_t)tok * Hdim + cc], v);
        }
    }
}

// ---------------- Host launch ----------------
extern "C" void kernel_launch(void* const* d_in, const int* in_sizes, int n_in,
                              void* d_out, int out_size, void* d_ws, size_t ws_size,
                              hipStream_t stream)
{
    const float* x  = (const float*)d_in[0];
    const float* gw = (const float*)d_in[1];
    const float* w1 = (const float*)d_in[2];
    const float* b1 = (const float*)d_in[3];
    const float* w2 = (const float*)d_in[4];
    const float* b2 = (const float*)d_in[5];
    float* out = (float*)d_out;

    // Workspace layout: [hid chunk][cnt(32B)][psum(32B)][ltok E*T][lw E*T]
    size_t fixed = 64 + (size_t)Edim * Tdim * 8;
    int CH = 2048;
    while ((size_t)CH * Ddim * 4 + fixed > ws_size && CH > 256) CH >>= 1;

    char* wsb = (char*)d_ws;
    float* hid  = (float*)wsb;
    size_t off  = (size_t)CH * Ddim * 4;
    int*   cnt  = (int*)(wsb + off);
    float* psum = (float*)(wsb + off + 32);
    int*   ltok = (int*)(wsb + off + 64);
    float* lwp  = (float*)(wsb + off + 64 + (size_t)Edim * Tdim * 4);

    hipMemsetAsync(cnt, 0, 64, stream);
    hipMemsetAsync(d_out, 0, (size_t)out_size * 4, stream);

    router_kernel<<<Tdim / 4, 256, 0, stream>>>(x, gw, cnt, psum, ltok, lwp);
    aux_kernel<<<1, 64, 0, stream>>>(cnt, psum, out + (size_t)Tdim * Hdim);

    int chunks = Tdim / CH;
    for (int e = 0; e < Edim; ++e) {
        for (int c = 0; c < chunks; ++c) {
            dim3 g1(Ddim / TN, CH / TM);
            gemm1_kernel<<<g1, 256, 0, stream>>>(x, w1, b1, cnt, ltok, hid, e, c * CH);
            dim3 g2(Hdim / TN, CH / TM);
            gemm2_kernel<<<g2, 256, 0, stream>>>(hid, w2, b2, cnt, ltok, lwp, out, e, c * CH);
        }
    }
}

// Round 2
// 756.238 us; speedup vs baseline: 5.2092x; 5.2092x over previous
//
#include <hip/hip_runtime.h>
#include <hip/hip_bf16.h>
#include <math.h>

#define Bdim 2
#define Sdim 4096
#define Hdim 1024
#define Edim 8
#define Ddim 2048
#define Tdim (Bdim*Sdim)   // 8192 tokens

#define BM 128
#define BN 128
#define BK 64
#define LDK 72   // BK + 8 pad -> row stride 144B (16B-aligned, 2-way bank = free)

typedef __attribute__((ext_vector_type(8))) __bf16 bfv8;
typedef __attribute__((ext_vector_type(8))) short s16x8;
typedef __attribute__((ext_vector_type(4))) short s16x4;
typedef __attribute__((ext_vector_type(4))) float f32x4;

__device__ __forceinline__ short f2bf(float f) {
    union { float f; unsigned u; } a; a.f = f;
    unsigned r = (a.u + 0x7fffu + ((a.u >> 16) & 1u)) >> 16;
    return (short)r;
}

// ---------------- Router: 64 blocks x 256 thr; wave handles 32 tokens ----------------
__global__ __launch_bounds__(256) void router_kernel(
    const float* __restrict__ x, const float* __restrict__ gw,
    int* __restrict__ cnt, float* __restrict__ psum,
    int* __restrict__ ltok, float* __restrict__ lw)
{
    __shared__ float gws[Edim * Hdim];          // 32 KB
    __shared__ int   lcnt[Edim], gbase[Edim];
    __shared__ int   s_e[256], s_pos[256], s_tok[256];
    __shared__ float s_w[256];
    __shared__ float s_ps[4][8];

    int tid = threadIdx.x;
    for (int i = tid; i < Edim * Hdim / 4; i += 256)
        ((float4*)gws)[i] = ((const float4*)gw)[i];
    if (tid < Edim) lcnt[tid] = 0;
    __syncthreads();

    int wave = tid >> 6, lane = tid & 63;
    double ps = 0.0;

    for (int i = 0; i < 32; ++i) {
        int t = blockIdx.x * 128 + wave * 32 + i;
        double acc[Edim];
#pragma unroll
        for (int e = 0; e < Edim; ++e) acc[e] = 0.0;
#pragma unroll
        for (int kq = 0; kq < 4; ++kq) {
            float4 xv = *(const float4*)(x + (size_t)t * Hdim + kq * 256 + lane * 4);
#pragma unroll
            for (int e = 0; e < Edim; ++e) {
                float4 wv = *(const float4*)(&gws[e * Hdim + kq * 256 + lane * 4]);
                acc[e] += (double)xv.x * wv.x + (double)xv.y * wv.y
                        + (double)xv.z * wv.z + (double)xv.w * wv.w;
            }
        }
#pragma unroll
        for (int e = 0; e < Edim; ++e) {
#pragma unroll
            for (int m = 32; m >= 1; m >>= 1)
                acc[e] += __shfl_xor(acc[e], m, 64);
        }
        // distribute: lane holds logit of expert (lane&7)
        int el = lane & 7;
        double v = acc[0];
#pragma unroll
        for (int e = 1; e < Edim; ++e) if (el == e) v = acc[e];
        double mx = v;
#pragma unroll
        for (int m = 1; m < 8; m <<= 1) mx = fmax(mx, __shfl_xor(mx, m, 8));
        double ex = exp(v - mx);
        double sm = ex;
#pragma unroll
        for (int m = 1; m < 8; m <<= 1) sm += __shfl_xor(sm, m, 8);
        double p = ex / sm;
        ps += p;
        double pe[8];
#pragma unroll
        for (int e = 0; e < 8; ++e) pe[e] = __shfl(p, e, 8);
        if (lane == 0) {
            double b1v = -1.0; int e1 = -1;
#pragma unroll
            for (int e = 0; e < 8; ++e) if (pe[e] > b1v) { b1v = pe[e]; e1 = e; }
            double b2v = -1.0; int e2 = -1;
#pragma unroll
            for (int e = 0; e < 8; ++e) if (e != e1 && pe[e] > b2v) { b2v = pe[e]; e2 = e; }
            double inv = 1.0 / (b1v + b2v);
            int lt = wave * 32 + i;
            int p1 = atomicAdd(&lcnt[e1], 1);
            s_e[2*lt] = e1; s_pos[2*lt] = p1; s_tok[2*lt] = t; s_w[2*lt] = (float)(b1v * inv);
            int p2 = atomicAdd(&lcnt[e2], 1);
            s_e[2*lt+1] = e2; s_pos[2*lt+1] = p2; s_tok[2*lt+1] = t; s_w[2*lt+1] = (float)(b2v * inv);
        }
    }
    if (lane < 8) s_ps[wave][lane] = (float)ps;
    __syncthreads();
    if (tid < 8) {
        atomicAdd(&psum[tid], s_ps[0][tid] + s_ps[1][tid] + s_ps[2][tid] + s_ps[3][tid]);
        gbase[tid] = atomicAdd(&cnt[tid], lcnt[tid]);
    }
    __syncthreads();
    {
        int e = s_e[tid];
        int pos = gbase[e] + s_pos[tid];
        ltok[e * Tdim + pos] = s_tok[tid];
        lw[e * Tdim + pos] = s_w[tid];
    }
}

// ---------------- Aux loss ----------------
__global__ void aux_kernel(const int* __restrict__ cnt,
                           const float* __restrict__ psum,
                           float* __restrict__ out_aux)
{
    if (threadIdx.x == 0 && blockIdx.x == 0) {
        double s = 0.0;
        for (int e = 0; e < Edim; ++e)
            s += ((double)cnt[e] / (double)Bdim) * ((double)psum[e] / (double)Tdim);
        out_aux[0] = (float)((double)Edim * s);
    }
}

// ---------------- GEMM1: hid = gelu(X[list] @ w1_e + b1) -> bf16 ----------------
__global__ __launch_bounds__(256) void gemm1_kernel(
    const float* __restrict__ x, const float* __restrict__ w1,
    const float* __restrict__ b1, const int* __restrict__ cnt,
    const int* __restrict__ ltok, short* __restrict__ hid,
    int CH, int row_base)
{
    int e = blockIdx.z;
    int n_e = cnt[e];
    int row0 = row_base + blockIdx.y * BM;
    if (row0 >= n_e) return;
    int col0 = blockIdx.x * BN;

    __shared__ short As[BM][LDK];
    __shared__ short Bs[BN][LDK];

    int tid = threadIdx.x;
    int arow = tid >> 1;
    int akh  = (tid & 1) * 32;
    int gr_a = row0 + arow;
    int tok = ltok[(size_t)e * Tdim + (gr_a < n_e ? gr_a : n_e - 1)];
    const float* xrow = x + (size_t)tok * Hdim + akh;
    int bdg = (tid & 31) * 4;
    int bkg = (tid >> 5) * 4;

    int lane = tid & 63;
    int wid = tid >> 6;
    int wm = (wid >> 1) * 64, wn = (wid & 1) * 64;
    int fr = lane & 15, kg = lane >> 4;

    f32x4 acc[4][4];
#pragma unroll
    for (int m = 0; m < 4; ++m)
#pragma unroll
        for (int n = 0; n < 4; ++n) acc[m][n] = (f32x4)0.0f;

    const float* wB = w1 + (size_t)e * Hdim * Ddim + col0;

    for (int k0 = 0; k0 < Hdim; k0 += BK) {
#pragma unroll
        for (int i = 0; i < 8; ++i) {
            float4 v = *(const float4*)(xrow + k0 + i * 4);
            s16x4 h; h[0] = f2bf(v.x); h[1] = f2bf(v.y); h[2] = f2bf(v.z); h[3] = f2bf(v.w);
            *(s16x4*)(&As[arow][akh + i * 4]) = h;
        }
#pragma unroll
        for (int r = 0; r < 2; ++r) {
            int kq = bkg + r * 32;
            float4 v0 = *(const float4*)(wB + (size_t)(k0 + kq + 0) * Ddim + bdg);
            float4 v1 = *(const float4*)(wB + (size_t)(k0 + kq + 1) * Ddim + bdg);
            float4 v2 = *(const float4*)(wB + (size_t)(k0 + kq + 2) * Ddim + bdg);
            float4 v3 = *(const float4*)(wB + (size_t)(k0 + kq + 3) * Ddim + bdg);
            const float* p0 = (const float*)&v0; const float* p1 = (const float*)&v1;
            const float* p2 = (const float*)&v2; const float* p3 = (const float*)&v3;
#pragma unroll
            for (int c = 0; c < 4; ++c) {
                s16x4 h; h[0] = f2bf(p0[c]); h[1] = f2bf(p1[c]); h[2] = f2bf(p2[c]); h[3] = f2bf(p3[c]);
                *(s16x4*)(&Bs[bdg + c][kq]) = h;
            }
        }
        __syncthreads();
        bfv8 af[4][2], bfr[4][2];
#pragma unroll
        for (int m = 0; m < 4; ++m)
#pragma unroll
            for (int kk = 0; kk < 2; ++kk)
                af[m][kk] = *(const bfv8*)(&As[wm + m * 16 + fr][kk * 32 + kg * 8]);
#pragma unroll
        for (int n = 0; n < 4; ++n)
#pragma unroll
            for (int kk = 0; kk < 2; ++kk)
                bfr[n][kk] = *(const bfv8*)(&Bs[wn + n * 16 + fr][kk * 32 + kg * 8]);
#pragma unroll
        for (int m = 0; m < 4; ++m)
#pragma unroll
            for (int n = 0; n < 4; ++n) {
                acc[m][n] = __builtin_amdgcn_mfma_f32_16x16x32_bf16(af[m][0], bfr[n][0], acc[m][n], 0, 0, 0);
                acc[m][n] = __builtin_amdgcn_mfma_f32_16x16x32_bf16(af[m][1], bfr[n][1], acc[m][n], 0, 0, 0);
            }
        __syncthreads();
    }

    int lr0 = row0 - row_base;
#pragma unroll
    for (int m = 0; m < 4; ++m) {
        int r0 = wm + m * 16 + kg * 4;
#pragma unroll
        for (int j = 0; j < 4; ++j) {
            int gr = row0 + r0 + j;
            if (gr >= n_e) continue;
            size_t hbase = ((size_t)e * CH + (size_t)(lr0 + r0 + j)) * Ddim;
#pragma unroll
            for (int n = 0; n < 4; ++n) {
                int col = col0 + wn + n * 16 + fr;
                float v = acc[m][n][j] + b1[e * Ddim + col];
                float g = 0.5f * v * (1.0f + erff(v * 0.70710678118654752440f));
                hid[hbase + col] = f2bf(g);
            }
        }
    }
}

// ---------------- GEMM2: out[tok] += p * (hid @ w2_e + b2) ----------------
__global__ __launch_bounds__(256) void gemm2_kernel(
    const short* __restrict__ hid, const float* __restrict__ w2,
    const float* __restrict__ b2, const int* __restrict__ cnt,
    const int* __restrict__ ltok, const float* __restrict__ lw,
    float* __restrict__ out, int CH, int row_base)
{
    int e = blockIdx.z;
    int n_e = cnt[e];
    int row0 = row_base + blockIdx.y * BM;
    if (row0 >= n_e) return;
    int col0 = blockIdx.x * BN;

    __shared__ short As[BM][LDK];
    __shared__ short Bs[BN][LDK];

    int tid = threadIdx.x;
    int arow = tid >> 1;
    int akh  = (tid & 1) * 32;
    const short* hrow = hid + ((size_t)e * CH + (size_t)(row0 - row_base + arow)) * Ddim + akh;
    int bdg = (tid & 31) * 4;
    int bkg = (tid >> 5) * 4;

    int lane = tid & 63;
    int wid = tid >> 6;
    int wm = (wid >> 1) * 64, wn = (wid & 1) * 64;
    int fr = lane & 15, kg = lane >> 4;

    f32x4 acc[4][4];
#pragma unroll
    for (int m = 0; m < 4; ++m)
#pragma unroll
        for (int n = 0; n < 4; ++n) acc[m][n] = (f32x4)0.0f;

    const float* wB = w2 + (size_t)e * Ddim * Hdim + col0;

    for (int k0 = 0; k0 < Ddim; k0 += BK) {
#pragma unroll
        for (int i = 0; i < 4; ++i) {
            s16x8 v = *(const s16x8*)(hrow + k0 + i * 8);
            *(s16x8*)(&As[arow][akh + i * 8]) = v;
        }
#pragma unroll
        for (int r = 0; r < 2; ++r) {
            int kq = bkg + r * 32;
            float4 v0 = *(const float4*)(wB + (size_t)(k0 + kq + 0) * Hdim + bdg);
            float4 v1 = *(const float4*)(wB + (size_t)(k0 + kq + 1) * Hdim + bdg);
            float4 v2 = *(const float4*)(wB + (size_t)(k0 + kq + 2) * Hdim + bdg);
            float4 v3 = *(const float4*)(wB + (size_t)(k0 + kq + 3) * Hdim + bdg);
            const float* p0 = (const float*)&v0; const float* p1 = (const float*)&v1;
            const float* p2 = (const float*)&v2; const float* p3 = (const float*)&v3;
#pragma unroll
            for (int c = 0; c < 4; ++c) {
                s16x4 h; h[0] = f2bf(p0[c]); h[1] = f2bf(p1[c]); h[2] = f2bf(p2[c]); h[3] = f2bf(p3[c]);
                *(s16x4*)(&Bs[bdg + c][kq]) = h;
            }
        }
        __syncthreads();
        bfv8 af[4][2], bfr[4][2];
#pragma unroll
        for (int m = 0; m < 4; ++m)
#pragma unroll
            for (int kk = 0; kk < 2; ++kk)
                af[m][kk] = *(const bfv8*)(&As[wm + m * 16 + fr][kk * 32 + kg * 8]);
#pragma unroll
        for (int n = 0; n < 4; ++n)
#pragma unroll
            for (int kk = 0; kk < 2; ++kk)
                bfr[n][kk] = *(const bfv8*)(&Bs[wn + n * 16 + fr][kk * 32 + kg * 8]);
#pragma unroll
        for (int m = 0; m < 4; ++m)
#pragma unroll
            for (int n = 0; n < 4; ++n) {
                acc[m][n] = __builtin_amdgcn_mfma_f32_16x16x32_bf16(af[m][0], bfr[n][0], acc[m][n], 0, 0, 0);
                acc[m][n] = __builtin_amdgcn_mfma_f32_16x16x32_bf16(af[m][1], bfr[n][1], acc[m][n], 0, 0, 0);
            }
        __syncthreads();
    }

#pragma unroll
    for (int m = 0; m < 4; ++m) {
        int r0 = wm + m * 16 + kg * 4;
#pragma unroll
        for (int j = 0; j < 4; ++j) {
            int gr = row0 + r0 + j;
            if (gr >= n_e) continue;
            int tok = ltok[(size_t)e * Tdim + gr];
            float p = lw[(size_t)e * Tdim + gr];
#pragma unroll
            for (int n = 0; n < 4; ++n) {
                int col = col0 + wn + n * 16 + fr;
                float v = p * (acc[m][n][j] + b2[e * Hdim + col]);
                atomicAdd(&out[(size_t)tok * Hdim + col], v);
            }
        }
    }
}

// ---------------- Host launch ----------------
extern "C" void kernel_launch(void* const* d_in, const int* in_sizes, int n_in,
                              void* d_out, int out_size, void* d_ws, size_t ws_size,
                              hipStream_t stream)
{
    const float* x  = (const float*)d_in[0];
    const float* gw = (const float*)d_in[1];
    const float* w1 = (const float*)d_in[2];
    const float* b1 = (const float*)d_in[3];
    const float* w2 = (const float*)d_in[4];
    const float* b2 = (const float*)d_in[5];
    float* out = (float*)d_out;

    // ws layout: [cnt 32][psum 32][ltok E*T*4][lw E*T*4][hid bf16 8*CH*D]
    char* wsb = (char*)d_ws;
    int*   cnt  = (int*)wsb;
    float* psum = (float*)(wsb + 32);
    int*   ltok = (int*)(wsb + 64);
    float* lwp  = (float*)(wsb + 64 + (size_t)Edim * Tdim * 4);
    size_t fixed = 64 + (size_t)Edim * Tdim * 8;
    short* hid  = (short*)(wsb + fixed);

    int CH = 2048;
    while (CH > 128 && fixed + (size_t)Edim * CH * Ddim * 2 > ws_size) CH >>= 1;

    hipMemsetAsync(wsb, 0, 64, stream);
    hipMemsetAsync(d_out, 0, (size_t)out_size * 4, stream);

    router_kernel<<<64, 256, 0, stream>>>(x, gw, cnt, psum, ltok, lwp);
    aux_kernel<<<1, 64, 0, stream>>>(cnt, psum, out + (size_t)Tdim * Hdim);

    int chunks = Tdim / CH;
    for (int c = 0; c < chunks; ++c) {
        dim3 g1(Ddim / BN, CH / BM, Edim);
        gemm1_kernel<<<g1, 256, 0, stream>>>(x, w1, b1, cnt, ltok, hid, CH, c * CH);
        dim3 g2(Hdim / BN, CH / BM, Edim);
        gemm2_kernel<<<g2, 256, 0, stream>>>(hid, w2, b2, cnt, ltok, lwp, out, CH, c * CH);
    }
}

// Round 3
// 624.809 us; speedup vs baseline: 6.3049x; 1.2103x over previous
//
#include <hip/hip_runtime.h>
#include <hip/hip_bf16.h>
#include <math.h>

#define Bdim 2
#define Sdim 4096
#define Hdim 1024
#define Edim 8
#define Ddim 2048
#define Tdim (Bdim*Sdim)   // 8192 tokens

typedef __attribute__((ext_vector_type(8))) __bf16 bfv8;
typedef __attribute__((ext_vector_type(8))) short s16x8;
typedef __attribute__((ext_vector_type(4))) short s16x4;
typedef __attribute__((ext_vector_type(4))) float f32x4;

__device__ __forceinline__ short f2bf(float f) {
    union { float f; unsigned u; } a; a.f = f;
    unsigned r = (a.u + 0x7fffu + ((a.u >> 16) & 1u)) >> 16;
    return (short)r;
}

typedef const __attribute__((address_space(1))) unsigned int ga_u32;
typedef __attribute__((address_space(3))) unsigned int la_u32;

__device__ __forceinline__ void gl_lds16(const void* g, void* l) {
    __builtin_amdgcn_global_load_lds((ga_u32*)g, (la_u32*)l, 16, 0, 0);
}

// ---------------- Router: 64 blocks x 256 thr; wave handles 32 tokens ----------------
__global__ __launch_bounds__(256) void router_kernel(
    const float* __restrict__ x, const float* __restrict__ gw,
    int* __restrict__ cnt, float* __restrict__ psum,
    int* __restrict__ ltok, float* __restrict__ lw)
{
    __shared__ float gws[Edim * Hdim];          // 32 KB
    __shared__ int   lcnt[Edim], gbase[Edim];
    __shared__ int   s_e[256], s_pos[256], s_tok[256];
    __shared__ float s_w[256];
    __shared__ float s_ps[4][8];

    int tid = threadIdx.x;
    for (int i = tid; i < Edim * Hdim / 4; i += 256)
        ((float4*)gws)[i] = ((const float4*)gw)[i];
    if (tid < Edim) lcnt[tid] = 0;
    __syncthreads();

    int wave = tid >> 6, lane = tid & 63;
    double ps = 0.0;

    for (int i = 0; i < 32; ++i) {
        int t = blockIdx.x * 128 + wave * 32 + i;
        double acc[Edim];
#pragma unroll
        for (int e = 0; e < Edim; ++e) acc[e] = 0.0;
#pragma unroll
        for (int kq = 0; kq < 4; ++kq) {
            float4 xv = *(const float4*)(x + (size_t)t * Hdim + kq * 256 + lane * 4);
#pragma unroll
            for (int e = 0; e < Edim; ++e) {
                float4 wv = *(const float4*)(&gws[e * Hdim + kq * 256 + lane * 4]);
                acc[e] += (double)xv.x * wv.x + (double)xv.y * wv.y
                        + (double)xv.z * wv.z + (double)xv.w * wv.w;
            }
        }
#pragma unroll
        for (int e = 0; e < Edim; ++e) {
#pragma unroll
            for (int m = 32; m >= 1; m >>= 1)
                acc[e] += __shfl_xor(acc[e], m, 64);
        }
        int el = lane & 7;
        double v = acc[0];
#pragma unroll
        for (int e = 1; e < Edim; ++e) if (el == e) v = acc[e];
        double mx = v;
#pragma unroll
        for (int m = 1; m < 8; m <<= 1) mx = fmax(mx, __shfl_xor(mx, m, 8));
        double ex = exp(v - mx);
        double sm = ex;
#pragma unroll
        for (int m = 1; m < 8; m <<= 1) sm += __shfl_xor(sm, m, 8);
        double p = ex / sm;
        ps += p;
        double pe[8];
#pragma unroll
        for (int e = 0; e < 8; ++e) pe[e] = __shfl(p, e, 8);
        if (lane == 0) {
            double b1v = -1.0; int e1 = -1;
#pragma unroll
            for (int e = 0; e < 8; ++e) if (pe[e] > b1v) { b1v = pe[e]; e1 = e; }
            double b2v = -1.0; int e2 = -1;
#pragma unroll
            for (int e = 0; e < 8; ++e) if (e != e1 && pe[e] > b2v) { b2v = pe[e]; e2 = e; }
            double inv = 1.0 / (b1v + b2v);
            int lt = wave * 32 + i;
            int p1 = atomicAdd(&lcnt[e1], 1);
            s_e[2*lt] = e1; s_pos[2*lt] = p1; s_tok[2*lt] = t; s_w[2*lt] = (float)(b1v * inv);
            int p2 = atomicAdd(&lcnt[e2], 1);
            s_e[2*lt+1] = e2; s_pos[2*lt+1] = p2; s_tok[2*lt+1] = t; s_w[2*lt+1] = (float)(b2v * inv);
        }
    }
    if (lane < 8) s_ps[wave][lane] = (float)ps;
    __syncthreads();
    if (tid < 8) {
        atomicAdd(&psum[tid], s_ps[0][tid] + s_ps[1][tid] + s_ps[2][tid] + s_ps[3][tid]);
        gbase[tid] = atomicAdd(&cnt[tid], lcnt[tid]);
    }
    __syncthreads();
    {
        int e = s_e[tid];
        int pos = gbase[e] + s_pos[tid];
        ltok[e * Tdim + pos] = s_tok[tid];
        lw[e * Tdim + pos] = s_w[tid];
    }
}

// ---------------- Aux loss ----------------
__global__ void aux_kernel(const int* __restrict__ cnt,
                           const float* __restrict__ psum,
                           float* __restrict__ out_aux)
{
    if (threadIdx.x == 0 && blockIdx.x == 0) {
        double s = 0.0;
        for (int e = 0; e < Edim; ++e)
            s += ((double)cnt[e] / (double)Bdim) * ((double)psum[e] / (double)Tdim);
        out_aux[0] = (float)((double)Edim * s);
    }
}

// ---------------- Prep: x fp32 -> bf16 ----------------
__global__ __launch_bounds__(256) void convx_kernel(const float* __restrict__ x,
                                                    short* __restrict__ xb)
{
    size_t i = ((size_t)blockIdx.x * 256 + threadIdx.x) * 8;
    float4 a = *(const float4*)(x + i);
    float4 b = *(const float4*)(x + i + 4);
    s16x8 o;
    o[0]=f2bf(a.x); o[1]=f2bf(a.y); o[2]=f2bf(a.z); o[3]=f2bf(a.w);
    o[4]=f2bf(b.x); o[5]=f2bf(b.y); o[6]=f2bf(b.z); o[7]=f2bf(b.w);
    *(s16x8*)(xb + i) = o;
}

// ---------------- Prep: transpose-convert w [E][R][C] fp32 -> wt [E][C][R] bf16 ----------------
__global__ __launch_bounds__(256) void convt_kernel(const float* __restrict__ w,
                                                    short* __restrict__ wt, int R, int C)
{
    int e = blockIdx.z;
    int r0 = blockIdx.y * 64, c0 = blockIdx.x * 64;
    __shared__ short t[64][76];
    int tid = threadIdx.x;
    {
        int r = tid >> 2, cs = (tid & 3) * 16;
        const float* src = w + ((size_t)e * R + r0 + r) * C + c0 + cs;
#pragma unroll
        for (int q = 0; q < 4; ++q) {
            float4 v = *(const float4*)(src + q * 4);
            s16x4 h; h[0]=f2bf(v.x); h[1]=f2bf(v.y); h[2]=f2bf(v.z); h[3]=f2bf(v.w);
            *(s16x4*)(&t[r][cs + q * 4]) = h;
        }
    }
    __syncthreads();
    {
        int c = tid >> 2, rs = (tid & 3) * 16;
        short tmp[16];
#pragma unroll
        for (int j = 0; j < 16; ++j) tmp[j] = t[rs + j][c];
        short* dst = wt + ((size_t)e * C + c0 + c) * R + r0 + rs;
        *(s16x8*)dst = *(s16x8*)tmp;
        *(s16x8*)(dst + 8) = *(s16x8*)(tmp + 8);
    }
}

// ---------------- Fast GEMM1: hid = gelu(Xb[list] @ w1t^T + b1) -> bf16 ----------------
__global__ __launch_bounds__(256) void gemm1f_kernel(
    const short* __restrict__ xb, const short* __restrict__ w1t,
    const float* __restrict__ b1, const int* __restrict__ cnt,
    const int* __restrict__ ltok, short* __restrict__ hid,
    int CH, int row_base)
{
    int e = blockIdx.z;
    int n_e = cnt[e];
    int row0 = row_base + blockIdx.y * 128;
    if (row0 >= n_e) return;
    int col0 = blockIdx.x * 128;

    __shared__ short As[128 * 64];
    __shared__ short Bs[128 * 64];

    int tid = threadIdx.x;
    int w = tid >> 6, lane = tid & 63;

    // staging: 16 chunks of 1KB; wave w owns chunks w*4..w*4+3; dest linear, source pre-swizzled
    const short* aSrc[4]; const short* bSrc[4];
    short* aDst[4]; short* bDst[4];
#pragma unroll
    for (int i = 0; i < 4; ++i) {
        int chunk = w * 4 + i;
        int idx = chunk * 64 + lane;           // 16B-chunk index in tile
        int row = idx >> 3, q = idx & 7;
        int sc = (q * 16) ^ ((row & 7) << 4);  // swizzled byte col
        int gr = row0 + row; if (gr > n_e - 1) gr = n_e - 1;
        int tok = ltok[(size_t)e * Tdim + gr];
        aSrc[i] = xb + (size_t)tok * Hdim + (sc >> 1);
        aDst[i] = As + chunk * 512;
        bSrc[i] = w1t + ((size_t)e * Ddim + col0 + row) * Hdim + (sc >> 1);
        bDst[i] = Bs + chunk * 512;
    }

    int fr = lane & 15, kg = lane >> 4;
    int wm = (w >> 1) * 64, wn = (w & 1) * 64;

    int pa[4][2], pb[4][2];
#pragma unroll
    for (int m = 0; m < 4; ++m) {
        int row = wm + m * 16 + fr;
        int swz = (row & 7) << 3;
#pragma unroll
        for (int ks = 0; ks < 2; ++ks)
            pa[m][ks] = row * 64 + ((ks * 32 + kg * 8) ^ swz);
    }
#pragma unroll
    for (int n = 0; n < 4; ++n) {
        int row = wn + n * 16 + fr;
        int swz = (row & 7) << 3;
#pragma unroll
        for (int ks = 0; ks < 2; ++ks)
            pb[n][ks] = row * 64 + ((ks * 32 + kg * 8) ^ swz);
    }

    f32x4 acc[4][4];
#pragma unroll
    for (int m = 0; m < 4; ++m)
#pragma unroll
        for (int n = 0; n < 4; ++n) acc[m][n] = (f32x4)0.0f;

    for (int k0 = 0; k0 < Hdim; k0 += 64) {
#pragma unroll
        for (int i = 0; i < 4; ++i) {
            gl_lds16(aSrc[i], aDst[i]);
            gl_lds16(bSrc[i], bDst[i]);
            aSrc[i] += 64; bSrc[i] += 64;
        }
        __syncthreads();
#pragma unroll
        for (int ks = 0; ks < 2; ++ks) {
            bfv8 af[4], bf[4];
#pragma unroll
            for (int m = 0; m < 4; ++m) af[m] = *(const bfv8*)(As + pa[m][ks]);
#pragma unroll
            for (int n = 0; n < 4; ++n) bf[n] = *(const bfv8*)(Bs + pb[n][ks]);
#pragma unroll
            for (int m = 0; m < 4; ++m)
#pragma unroll
                for (int n = 0; n < 4; ++n)
                    acc[m][n] = __builtin_amdgcn_mfma_f32_16x16x32_bf16(af[m], bf[n], acc[m][n], 0, 0, 0);
        }
        __syncthreads();
    }

    int lr0 = row0 - row_base;
#pragma unroll
    for (int m = 0; m < 4; ++m) {
        int r0r = wm + m * 16 + kg * 4;
#pragma unroll
        for (int j = 0; j < 4; ++j) {
            int gr = row0 + r0r + j;
            if (gr >= n_e) continue;
            size_t hbase = ((size_t)e * CH + (size_t)(lr0 + r0r + j)) * Ddim;
#pragma unroll
            for (int n = 0; n < 4; ++n) {
                int col = col0 + wn + n * 16 + fr;
                float v = acc[m][n][j] + b1[e * Ddim + col];
                float g = 0.5f * v * (1.0f + erff(v * 0.70710678118654752440f));
                hid[hbase + col] = f2bf(g);
            }
        }
    }
}

// ---------------- Fast GEMM2: out[tok] += p * (hid @ w2t^T + b2) ----------------
__global__ __launch_bounds__(256) void gemm2f_kernel(
    const short* __restrict__ hid, const short* __restrict__ w2t,
    const float* __restrict__ b2, const int* __restrict__ cnt,
    const int* __restrict__ ltok, const float* __restrict__ lw,
    float* __restrict__ out, int CH, int row_base)
{
    int e = blockIdx.z;
    int n_e = cnt[e];
    int row0 = row_base + blockIdx.y * 128;
    if (row0 >= n_e) return;
    int col0 = blockIdx.x * 128;
    int lr0 = row0 - row_base;

    __shared__ short As[128 * 64];
    __shared__ short Bs[128 * 64];

    int tid = threadIdx.x;
    int w = tid >> 6, lane = tid & 63;

    const short* aSrc[4]; const short* bSrc[4];
    short* aDst[4]; short* bDst[4];
#pragma unroll
    for (int i = 0; i < 4; ++i) {
        int chunk = w * 4 + i;
        int idx = chunk * 64 + lane;
        int row = idx >> 3, q = idx & 7;
        int sc = (q * 16) ^ ((row & 7) << 4);
        aSrc[i] = hid + ((size_t)e * CH + (size_t)(lr0 + row)) * Ddim + (sc >> 1);
        aDst[i] = As + chunk * 512;
        bSrc[i] = w2t + ((size_t)e * Hdim + col0 + row) * Ddim + (sc >> 1);
        bDst[i] = Bs + chunk * 512;
    }

    int fr = lane & 15, kg = lane >> 4;
    int wm = (w >> 1) * 64, wn = (w & 1) * 64;

    int pa[4][2], pb[4][2];
#pragma unroll
    for (int m = 0; m < 4; ++m) {
        int row = wm + m * 16 + fr;
        int swz = (row & 7) << 3;
#pragma unroll
        for (int ks = 0; ks < 2; ++ks)
            pa[m][ks] = row * 64 + ((ks * 32 + kg * 8) ^ swz);
    }
#pragma unroll
    for (int n = 0; n < 4; ++n) {
        int row = wn + n * 16 + fr;
        int swz = (row & 7) << 3;
#pragma unroll
        for (int ks = 0; ks < 2; ++ks)
            pb[n][ks] = row * 64 + ((ks * 32 + kg * 8) ^ swz);
    }

    f32x4 acc[4][4];
#pragma unroll
    for (int m = 0; m < 4; ++m)
#pragma unroll
        for (int n = 0; n < 4; ++n) acc[m][n] = (f32x4)0.0f;

    for (int k0 = 0; k0 < Ddim; k0 += 64) {
#pragma unroll
        for (int i = 0; i < 4; ++i) {
            gl_lds16(aSrc[i], aDst[i]);
            gl_lds16(bSrc[i], bDst[i]);
            aSrc[i] += 64; bSrc[i] += 64;
        }
        __syncthreads();
#pragma unroll
        for (int ks = 0; ks < 2; ++ks) {
            bfv8 af[4], bf[4];
#pragma unroll
            for (int m = 0; m < 4; ++m) af[m] = *(const bfv8*)(As + pa[m][ks]);
#pragma unroll
            for (int n = 0; n < 4; ++n) bf[n] = *(const bfv8*)(Bs + pb[n][ks]);
#pragma unroll
            for (int m = 0; m < 4; ++m)
#pragma unroll
                for (int n = 0; n < 4; ++n)
                    acc[m][n] = __builtin_amdgcn_mfma_f32_16x16x32_bf16(af[m], bf[n], acc[m][n], 0, 0, 0);
        }
        __syncthreads();
    }

#pragma unroll
    for (int m = 0; m < 4; ++m) {
        int r0r = wm + m * 16 + kg * 4;
#pragma unroll
        for (int j = 0; j < 4; ++j) {
            int gr = row0 + r0r + j;
            if (gr >= n_e) continue;
            int tok = ltok[(size_t)e * Tdim + gr];
            float p = lw[(size_t)e * Tdim + gr];
#pragma unroll
            for (int n = 0; n < 4; ++n) {
                int col = col0 + wn + n * 16 + fr;
                float v = p * (acc[m][n][j] + b2[e * Hdim + col]);
                atomicAdd(&out[(size_t)tok * Hdim + col], v);
            }
        }
    }
}

// ================= Fallback (round-2 verified) kernels =================
#define FBK 64
#define FLDK 72

__global__ __launch_bounds__(256) void gemm1_fb(
    const float* __restrict__ x, const float* __restrict__ w1,
    const float* __restrict__ b1, const int* __restrict__ cnt,
    const int* __restrict__ ltok, short* __restrict__ hid,
    int CH, int row_base)
{
    int e = blockIdx.z;
    int n_e = cnt[e];
    int row0 = row_base + blockIdx.y * 128;
    if (row0 >= n_e) return;
    int col0 = blockIdx.x * 128;

    __shared__ short As[128][FLDK];
    __shared__ short Bs[128][FLDK];

    int tid = threadIdx.x;
    int arow = tid >> 1;
    int akh  = (tid & 1) * 32;
    int gr_a = row0 + arow;
    int tok = ltok[(size_t)e * Tdim + (gr_a < n_e ? gr_a : n_e - 1)];
    const float* xrow = x + (size_t)tok * Hdim + akh;
    int bdg = (tid & 31) * 4;
    int bkg = (tid >> 5) * 4;

    int lane = tid & 63;
    int wid = tid >> 6;
    int wm = (wid >> 1) * 64, wn = (wid & 1) * 64;
    int fr = lane & 15, kg = lane >> 4;

    f32x4 acc[4][4];
#pragma unroll
    for (int m = 0; m < 4; ++m)
#pragma unroll
        for (int n = 0; n < 4; ++n) acc[m][n] = (f32x4)0.0f;

    const float* wB = w1 + (size_t)e * Hdim * Ddim + col0;

    for (int k0 = 0; k0 < Hdim; k0 += FBK) {
#pragma unroll
        for (int i = 0; i < 8; ++i) {
            float4 v = *(const float4*)(xrow + k0 + i * 4);
            s16x4 h; h[0] = f2bf(v.x); h[1] = f2bf(v.y); h[2] = f2bf(v.z); h[3] = f2bf(v.w);
            *(s16x4*)(&As[arow][akh + i * 4]) = h;
        }
#pragma unroll
        for (int r = 0; r < 2; ++r) {
            int kq = bkg + r * 32;
            float4 v0 = *(const float4*)(wB + (size_t)(k0 + kq + 0) * Ddim + bdg);
            float4 v1 = *(const float4*)(wB + (size_t)(k0 + kq + 1) * Ddim + bdg);
            float4 v2 = *(const float4*)(wB + (size_t)(k0 + kq + 2) * Ddim + bdg);
            float4 v3 = *(const float4*)(wB + (size_t)(k0 + kq + 3) * Ddim + bdg);
            const float* p0 = (const float*)&v0; const float* p1 = (const float*)&v1;
            const float* p2 = (const float*)&v2; const float* p3 = (const float*)&v3;
#pragma unroll
            for (int c = 0; c < 4; ++c) {
                s16x4 h; h[0] = f2bf(p0[c]); h[1] = f2bf(p1[c]); h[2] = f2bf(p2[c]); h[3] = f2bf(p3[c]);
                *(s16x4*)(&Bs[bdg + c][kq]) = h;
            }
        }
        __syncthreads();
        bfv8 af[4][2], bfr[4][2];
#pragma unroll
        for (int m = 0; m < 4; ++m)
#pragma unroll
            for (int kk = 0; kk < 2; ++kk)
                af[m][kk] = *(const bfv8*)(&As[wm + m * 16 + fr][kk * 32 + kg * 8]);
#pragma unroll
        for (int n = 0; n < 4; ++n)
#pragma unroll
            for (int kk = 0; kk < 2; ++kk)
                bfr[n][kk] = *(const bfv8*)(&Bs[wn + n * 16 + fr][kk * 32 + kg * 8]);
#pragma unroll
        for (int m = 0; m < 4; ++m)
#pragma unroll
            for (int n = 0; n < 4; ++n) {
                acc[m][n] = __builtin_amdgcn_mfma_f32_16x16x32_bf16(af[m][0], bfr[n][0], acc[m][n], 0, 0, 0);
                acc[m][n] = __builtin_amdgcn_mfma_f32_16x16x32_bf16(af[m][1], bfr[n][1], acc[m][n], 0, 0, 0);
            }
        __syncthreads();
    }

    int lr0 = row0 - row_base;
#pragma unroll
    for (int m = 0; m < 4; ++m) {
        int r0r = wm + m * 16 + kg * 4;
#pragma unroll
        for (int j = 0; j < 4; ++j) {
            int gr = row0 + r0r + j;
            if (gr >= n_e) continue;
            size_t hbase = ((size_t)e * CH + (size_t)(lr0 + r0r + j)) * Ddim;
#pragma unroll
            for (int n = 0; n < 4; ++n) {
                int col = col0 + wn + n * 16 + fr;
                float v = acc[m][n][j] + b1[e * Ddim + col];
                float g = 0.5f * v * (1.0f + erff(v * 0.70710678118654752440f));
                hid[hbase + col] = f2bf(g);
            }
        }
    }
}

__global__ __launch_bounds__(256) void gemm2_fb(
    const short* __restrict__ hid, const float* __restrict__ w2,
    const float* __restrict__ b2, const int* __restrict__ cnt,
    const int* __restrict__ ltok, const float* __restrict__ lw,
    float* __restrict__ out, int CH, int row_base)
{
    int e = blockIdx.z;
    int n_e = cnt[e];
    int row0 = row_base + blockIdx.y * 128;
    if (row0 >= n_e) return;
    int col0 = blockIdx.x * 128;

    __shared__ short As[128][FLDK];
    __shared__ short Bs[128][FLDK];

    int tid = threadIdx.x;
    int arow = tid >> 1;
    int akh  = (tid & 1) * 32;
    const short* hrow = hid + ((size_t)e * CH + (size_t)(row0 - row_base + arow)) * Ddim + akh;
    int bdg = (tid & 31) * 4;
    int bkg = (tid >> 5) * 4;

    int lane = tid & 63;
    int wid = tid >> 6;
    int wm = (wid >> 1) * 64, wn = (wid & 1) * 64;
    int fr = lane & 15, kg = lane >> 4;

    f32x4 acc[4][4];
#pragma unroll
    for (int m = 0; m < 4; ++m)
#pragma unroll
        for (int n = 0; n < 4; ++n) acc[m][n] = (f32x4)0.0f;

    const float* wB = w2 + (size_t)e * Ddim * Hdim + col0;

    for (int k0 = 0; k0 < Ddim; k0 += FBK) {
#pragma unroll
        for (int i = 0; i < 4; ++i) {
            s16x8 v = *(const s16x8*)(hrow + k0 + i * 8);
            *(s16x8*)(&As[arow][akh + i * 8]) = v;
        }
#pragma unroll
        for (int r = 0; r < 2; ++r) {
            int kq = bkg + r * 32;
            float4 v0 = *(const float4*)(wB + (size_t)(k0 + kq + 0) * Hdim + bdg);
            float4 v1 = *(const float4*)(wB + (size_t)(k0 + kq + 1) * Hdim + bdg);
            float4 v2 = *(const float4*)(wB + (size_t)(k0 + kq + 2) * Hdim + bdg);
            float4 v3 = *(const float4*)(wB + (size_t)(k0 + kq + 3) * Hdim + bdg);
            const float* p0 = (const float*)&v0; const float* p1 = (const float*)&v1;
            const float* p2 = (const float*)&v2; const float* p3 = (const float*)&v3;
#pragma unroll
            for (int c = 0; c < 4; ++c) {
                s16x4 h; h[0] = f2bf(p0[c]); h[1] = f2bf(p1[c]); h[2] = f2bf(p2[c]); h[3] = f2bf(p3[c]);
                *(s16x4*)(&Bs[bdg + c][kq]) = h;
            }
        }
        __syncthreads();
        bfv8 af[4][2], bfr[4][2];
#pragma unroll
        for (int m = 0; m < 4; ++m)
#pragma unroll
            for (int kk = 0; kk < 2; ++kk)
                af[m][kk] = *(const bfv8*)(&As[wm + m * 16 + fr][kk * 32 + kg * 8]);
#pragma unroll
        for (int n = 0; n < 4; ++n)
#pragma unroll
            for (int kk = 0; kk < 2; ++kk)
                bfr[n][kk] = *(const bfv8*)(&Bs[wn + n * 16 + fr][kk * 32 + kg * 8]);
#pragma unroll
        for (int m = 0; m < 4; ++m)
#pragma unroll
            for (int n = 0; n < 4; ++n) {
                acc[m][n] = __builtin_amdgcn_mfma_f32_16x16x32_bf16(af[m][0], bfr[n][0], acc[m][n], 0, 0, 0);
                acc[m][n] = __builtin_amdgcn_mfma_f32_16x16x32_bf16(af[m][1], bfr[n][1], acc[m][n], 0, 0, 0);
            }
        __syncthreads();
    }

#pragma unroll
    for (int m = 0; m < 4; ++m) {
        int r0r = wm + m * 16 + kg * 4;
#pragma unroll
        for (int j = 0; j < 4; ++j) {
            int gr = row0 + r0r + j;
            if (gr >= n_e) continue;
            int tok = ltok[(size_t)e * Tdim + gr];
            float p = lw[(size_t)e * Tdim + gr];
#pragma unroll
            for (int n = 0; n < 4; ++n) {
                int col = col0 + wn + n * 16 + fr;
                float v = p * (acc[m][n][j] + b2[e * Hdim + col]);
                atomicAdd(&out[(size_t)tok * Hdim + col], v);
            }
        }
    }
}

// ---------------- Host launch ----------------
extern "C" void kernel_launch(void* const* d_in, const int* in_sizes, int n_in,
                              void* d_out, int out_size, void* d_ws, size_t ws_size,
                              hipStream_t stream)
{
    const float* x  = (const float*)d_in[0];
    const float* gw = (const float*)d_in[1];
    const float* w1 = (const float*)d_in[2];
    const float* b1 = (const float*)d_in[3];
    const float* w2 = (const float*)d_in[4];
    const float* b2 = (const float*)d_in[5];
    float* out = (float*)d_out;

    char* wsb = (char*)d_ws;
    size_t lists = 64 + (size_t)Edim * Tdim * 8;
    size_t xb_sz = (size_t)Tdim * Hdim * 2;
    size_t w_sz  = (size_t)Edim * Hdim * Ddim * 2;

    int CH = 2048;
    while (CH > 256 && lists + xb_sz + 2 * w_sz + (size_t)Edim * CH * Ddim * 2 > ws_size)
        CH >>= 1;
    bool fast = lists + xb_sz + 2 * w_sz + (size_t)Edim * CH * Ddim * 2 <= ws_size;

    int*   cnt  = (int*)wsb;
    float* psum = (float*)(wsb + 32);
    int*   ltok = (int*)(wsb + 64);
    float* lwp  = (float*)(wsb + 64 + (size_t)Edim * Tdim * 4);

    hipMemsetAsync(wsb, 0, 64, stream);
    hipMemsetAsync(d_out, 0, (size_t)out_size * 4, stream);

    if (fast) {
        short* xb  = (short*)(wsb + lists);
        short* w1t = (short*)(wsb + lists + xb_sz);
        short* w2t = (short*)(wsb + lists + xb_sz + w_sz);
        short* hid = (short*)(wsb + lists + xb_sz + 2 * w_sz);

        convx_kernel<<<Tdim * Hdim / 2048, 256, 0, stream>>>(x, xb);
        convt_kernel<<<dim3(Ddim / 64, Hdim / 64, Edim), 256, 0, stream>>>(w1, w1t, Hdim, Ddim);
        convt_kernel<<<dim3(Hdim / 64, Ddim / 64, Edim), 256, 0, stream>>>(w2, w2t, Ddim, Hdim);
        router_kernel<<<64, 256, 0, stream>>>(x, gw, cnt, psum, ltok, lwp);
        aux_kernel<<<1, 64, 0, stream>>>(cnt, psum, out + (size_t)Tdim * Hdim);

        int chunks = Tdim / CH;
        for (int c = 0; c < chunks; ++c) {
            gemm1f_kernel<<<dim3(Ddim / 128, CH / 128, Edim), 256, 0, stream>>>(
                xb, w1t, b1, cnt, ltok, hid, CH, c * CH);
            gemm2f_kernel<<<dim3(Hdim / 128, CH / 128, Edim), 256, 0, stream>>>(
                hid, w2t, b2, cnt, ltok, lwp, out, CH, c * CH);
        }
    } else {
        // round-2 verified path
        size_t fixed = lists;
        short* hid = (short*)(wsb + fixed);
        int CH2 = 2048;
        while (CH2 > 128 && fixed + (size_t)Edim * CH2 * Ddim * 2 > ws_size) CH2 >>= 1;

        router_kernel<<<64, 256, 0, stream>>>(x, gw, cnt, psum, ltok, lwp);
        aux_kernel<<<1, 64, 0, stream>>>(cnt, psum, out + (size_t)Tdim * Hdim);

        int chunks = Tdim / CH2;
        for (int c = 0; c < chunks; ++c) {
            gemm1_fb<<<dim3(Ddim / 128, CH2 / 128, Edim), 256, 0, stream>>>(
                x, w1, b1, cnt, ltok, hid, CH2, c * CH2);
            gemm2_fb<<<dim3(Hdim / 128, CH2 / 128, Edim), 256, 0, stream>>>(
                hid, w2, b2, cnt, ltok, lwp, out, CH2, c * CH2);
        }
    }
}

// Round 4
// 587.594 us; speedup vs baseline: 6.7042x; 1.0633x over previous
//
#include <hip/hip_runtime.h>
#include <hip/hip_bf16.h>
#include <math.h>

#define Bdim 2
#define Sdim 4096
#define Hdim 1024
#define Edim 8
#define Ddim 2048
#define Tdim (Bdim*Sdim)   // 8192 tokens

typedef __attribute__((ext_vector_type(8))) __bf16 bfv8;
typedef __attribute__((ext_vector_type(8))) short s16x8;
typedef __attribute__((ext_vector_type(4))) short s16x4;
typedef __attribute__((ext_vector_type(4))) float f32x4;

__device__ __forceinline__ short f2bf(float f) {
    union { float f; unsigned u; } a; a.f = f;
    unsigned r = (a.u + 0x7fffu + ((a.u >> 16) & 1u)) >> 16;
    return (short)r;
}

typedef const __attribute__((address_space(1))) unsigned int ga_u32;
typedef __attribute__((address_space(3))) unsigned int la_u32;

__device__ __forceinline__ void gl_lds16(const void* g, void* l) {
    __builtin_amdgcn_global_load_lds((ga_u32*)g, (la_u32*)l, 16, 0, 0);
}

// one barrier + one counted-drain per K-step (T3 minimum 2-phase)
#define SYNC_PREF() do {                                   \
    asm volatile("s_waitcnt vmcnt(0)" ::: "memory");       \
    __builtin_amdgcn_s_barrier();                          \
    __builtin_amdgcn_sched_barrier(0);                     \
} while (0)

// ---------------- Router: 64 blocks x 256 thr; wave handles 32 tokens ----------------
__global__ __launch_bounds__(256) void router_kernel(
    const float* __restrict__ x, const float* __restrict__ gw,
    int* __restrict__ cnt, float* __restrict__ psum,
    int* __restrict__ ltok, float* __restrict__ lw)
{
    __shared__ float gws[Edim * Hdim];          // 32 KB
    __shared__ int   lcnt[Edim], gbase[Edim];
    __shared__ int   s_e[256], s_pos[256], s_tok[256];
    __shared__ float s_w[256];
    __shared__ float s_ps[4][8];

    int tid = threadIdx.x;
    for (int i = tid; i < Edim * Hdim / 4; i += 256)
        ((float4*)gws)[i] = ((const float4*)gw)[i];
    if (tid < Edim) lcnt[tid] = 0;
    __syncthreads();

    int wave = tid >> 6, lane = tid & 63;
    double ps = 0.0;

    for (int i = 0; i < 32; ++i) {
        int t = blockIdx.x * 128 + wave * 32 + i;
        double acc[Edim];
#pragma unroll
        for (int e = 0; e < Edim; ++e) acc[e] = 0.0;
#pragma unroll
        for (int kq = 0; kq < 4; ++kq) {
            float4 xv = *(const float4*)(x + (size_t)t * Hdim + kq * 256 + lane * 4);
#pragma unroll
            for (int e = 0; e < Edim; ++e) {
                float4 wv = *(const float4*)(&gws[e * Hdim + kq * 256 + lane * 4]);
                acc[e] += (double)xv.x * wv.x + (double)xv.y * wv.y
                        + (double)xv.z * wv.z + (double)xv.w * wv.w;
            }
        }
#pragma unroll
        for (int e = 0; e < Edim; ++e) {
#pragma unroll
            for (int m = 32; m >= 1; m >>= 1)
                acc[e] += __shfl_xor(acc[e], m, 64);
        }
        int el = lane & 7;
        double v = acc[0];
#pragma unroll
        for (int e = 1; e < Edim; ++e) if (el == e) v = acc[e];
        double mx = v;
#pragma unroll
        for (int m = 1; m < 8; m <<= 1) mx = fmax(mx, __shfl_xor(mx, m, 8));
        double ex = exp(v - mx);
        double sm = ex;
#pragma unroll
        for (int m = 1; m < 8; m <<= 1) sm += __shfl_xor(sm, m, 8);
        double p = ex / sm;
        ps += p;
        double pe[8];
#pragma unroll
        for (int e = 0; e < 8; ++e) pe[e] = __shfl(p, e, 8);
        if (lane == 0) {
            double b1v = -1.0; int e1 = -1;
#pragma unroll
            for (int e = 0; e < 8; ++e) if (pe[e] > b1v) { b1v = pe[e]; e1 = e; }
            double b2v = -1.0; int e2 = -1;
#pragma unroll
            for (int e = 0; e < 8; ++e) if (e != e1 && pe[e] > b2v) { b2v = pe[e]; e2 = e; }
            double inv = 1.0 / (b1v + b2v);
            int lt = wave * 32 + i;
            int p1 = atomicAdd(&lcnt[e1], 1);
            s_e[2*lt] = e1; s_pos[2*lt] = p1; s_tok[2*lt] = t; s_w[2*lt] = (float)(b1v * inv);
            int p2 = atomicAdd(&lcnt[e2], 1);
            s_e[2*lt+1] = e2; s_pos[2*lt+1] = p2; s_tok[2*lt+1] = t; s_w[2*lt+1] = (float)(b2v * inv);
        }
    }
    if (lane < 8) s_ps[wave][lane] = (float)ps;
    __syncthreads();
    if (tid < 8) {
        atomicAdd(&psum[tid], s_ps[0][tid] + s_ps[1][tid] + s_ps[2][tid] + s_ps[3][tid]);
        gbase[tid] = atomicAdd(&cnt[tid], lcnt[tid]);
    }
    __syncthreads();
    {
        int e = s_e[tid];
        int pos = gbase[e] + s_pos[tid];
        ltok[e * Tdim + pos] = s_tok[tid];
        lw[e * Tdim + pos] = s_w[tid];
    }
}

// ---------------- Aux loss ----------------
__global__ void aux_kernel(const int* __restrict__ cnt,
                           const float* __restrict__ psum,
                           float* __restrict__ out_aux)
{
    if (threadIdx.x == 0 && blockIdx.x == 0) {
        double s = 0.0;
        for (int e = 0; e < Edim; ++e)
            s += ((double)cnt[e] / (double)Bdim) * ((double)psum[e] / (double)Tdim);
        out_aux[0] = (float)((double)Edim * s);
    }
}

// ---------------- Prep: x fp32 -> bf16 ----------------
__global__ __launch_bounds__(256) void convx_kernel(const float* __restrict__ x,
                                                    short* __restrict__ xb)
{
    size_t i = ((size_t)blockIdx.x * 256 + threadIdx.x) * 8;
    float4 a = *(const float4*)(x + i);
    float4 b = *(const float4*)(x + i + 4);
    s16x8 o;
    o[0]=f2bf(a.x); o[1]=f2bf(a.y); o[2]=f2bf(a.z); o[3]=f2bf(a.w);
    o[4]=f2bf(b.x); o[5]=f2bf(b.y); o[6]=f2bf(b.z); o[7]=f2bf(b.w);
    *(s16x8*)(xb + i) = o;
}

// ---------------- Prep: transpose-convert w [E][R][C] fp32 -> wt [E][C][R] bf16 ----------------
__global__ __launch_bounds__(256) void convt_kernel(const float* __restrict__ w,
                                                    short* __restrict__ wt, int R, int C)
{
    int e = blockIdx.z;
    int r0 = blockIdx.y * 64, c0 = blockIdx.x * 64;
    __shared__ short t[64][76];
    int tid = threadIdx.x;
    {
        int r = tid >> 2, cs = (tid & 3) * 16;
        const float* src = w + ((size_t)e * R + r0 + r) * C + c0 + cs;
#pragma unroll
        for (int q = 0; q < 4; ++q) {
            float4 v = *(const float4*)(src + q * 4);
            s16x4 h; h[0]=f2bf(v.x); h[1]=f2bf(v.y); h[2]=f2bf(v.z); h[3]=f2bf(v.w);
            *(s16x4*)(&t[r][cs + q * 4]) = h;
        }
    }
    __syncthreads();
    {
        int c = tid >> 2, rs = (tid & 3) * 16;
        short tmp[16];
#pragma unroll
        for (int j = 0; j < 16; ++j) tmp[j] = t[rs + j][c];
        short* dst = wt + ((size_t)e * C + c0 + c) * R + r0 + rs;
        *(s16x8*)dst = *(s16x8*)tmp;
        *(s16x8*)(dst + 8) = *(s16x8*)(tmp + 8);
    }
}

// ---------------- Fast GEMM1: hid = gelu(Xb[list] @ w1t^T + b1) -> bf16 ----------------
// dbuf 2-phase, XCD==expert swizzle
__global__ __launch_bounds__(256) void gemm1f_kernel(
    const short* __restrict__ xb, const short* __restrict__ w1t,
    const float* __restrict__ b1, const int* __restrict__ cnt,
    const int* __restrict__ ltok, short* __restrict__ hid,
    int CH, int row_base)
{
    constexpr int GX = Ddim / 128;  // 16
    int orig = blockIdx.x + GX * (blockIdx.y + gridDim.y * blockIdx.z);
    int e = orig & 7;               // expert == XCD (consecutive ids round-robin XCDs)
    unsigned rem = (unsigned)orig >> 3;
    int by = rem / GX, bx = rem & (GX - 1);

    int n_e = cnt[e];
    int row0 = row_base + by * 128;
    if (row0 >= n_e) return;
    int col0 = bx * 128;

    __shared__ short lds[4 * 128 * 64];   // As0 Bs0 As1 Bs1
    short* As0 = lds;
    short* Bs0 = lds + 8192;
    short* As1 = lds + 16384;
    short* Bs1 = lds + 24576;

    int tid = threadIdx.x;
    int w = tid >> 6, lane = tid & 63;

    const short* aSrc[4]; const short* bSrc[4];
    int dOff[4];
#pragma unroll
    for (int i = 0; i < 4; ++i) {
        int chunk = w * 4 + i;
        int idx = chunk * 64 + lane;           // 16B-chunk index in tile
        int row = idx >> 3, q = idx & 7;
        int sc = (q * 16) ^ ((row & 7) << 4);  // swizzled byte col
        int gr = row0 + row; if (gr > n_e - 1) gr = n_e - 1;
        int tok = ltok[(size_t)e * Tdim + gr];
        aSrc[i] = xb + (size_t)tok * Hdim + (sc >> 1);
        bSrc[i] = w1t + ((size_t)e * Ddim + col0 + row) * Hdim + (sc >> 1);
        dOff[i] = chunk * 512;
    }

    int fr = lane & 15, kg = lane >> 4;
    int wm = (w >> 1) * 64, wn = (w & 1) * 64;

    int pa[4][2], pb[4][2];
#pragma unroll
    for (int m = 0; m < 4; ++m) {
        int row = wm + m * 16 + fr;
        int swz = (row & 7) << 3;
#pragma unroll
        for (int ks = 0; ks < 2; ++ks)
            pa[m][ks] = row * 64 + ((ks * 32 + kg * 8) ^ swz);
    }
#pragma unroll
    for (int n = 0; n < 4; ++n) {
        int row = wn + n * 16 + fr;
        int swz = (row & 7) << 3;
#pragma unroll
        for (int ks = 0; ks < 2; ++ks)
            pb[n][ks] = row * 64 + ((ks * 32 + kg * 8) ^ swz);
    }

    f32x4 acc[4][4];
#pragma unroll
    for (int m = 0; m < 4; ++m)
#pragma unroll
        for (int n = 0; n < 4; ++n) acc[m][n] = (f32x4)0.0f;

    auto stage = [&](short* aB, short* bB) {
#pragma unroll
        for (int i = 0; i < 4; ++i) {
            gl_lds16(aSrc[i], aB + dOff[i]);
            gl_lds16(bSrc[i], bB + dOff[i]);
            aSrc[i] += 64; bSrc[i] += 64;
        }
    };
    auto compute = [&](const short* aB, const short* bB) {
#pragma unroll
        for (int ks = 0; ks < 2; ++ks) {
            bfv8 af[4], bf[4];
#pragma unroll
            for (int m = 0; m < 4; ++m) af[m] = *(const bfv8*)(aB + pa[m][ks]);
#pragma unroll
            for (int n = 0; n < 4; ++n) bf[n] = *(const bfv8*)(bB + pb[n][ks]);
#pragma unroll
            for (int m = 0; m < 4; ++m)
#pragma unroll
                for (int n = 0; n < 4; ++n)
                    acc[m][n] = __builtin_amdgcn_mfma_f32_16x16x32_bf16(af[m], bf[n], acc[m][n], 0, 0, 0);
        }
    };

    constexpr int NK = Hdim / 64;   // 16 (even)
    stage(As0, Bs0);                // tile 0
    SYNC_PREF();
    for (int k = 0; k < NK; k += 2) {
        stage(As1, Bs1);            // prefetch tile k+1
        compute(As0, Bs0);          // tile k
        __builtin_amdgcn_sched_barrier(0);
        SYNC_PREF();
        if (k + 2 < NK) stage(As0, Bs0);   // prefetch tile k+2
        compute(As1, Bs1);          // tile k+1
        __builtin_amdgcn_sched_barrier(0);
        SYNC_PREF();
    }

    int lr0 = row0 - row_base;
#pragma unroll
    for (int m = 0; m < 4; ++m) {
        int r0r = wm + m * 16 + kg * 4;
#pragma unroll
        for (int j = 0; j < 4; ++j) {
            int gr = row0 + r0r + j;
            if (gr >= n_e) continue;
            size_t hbase = ((size_t)e * CH + (size_t)(lr0 + r0r + j)) * Ddim;
#pragma unroll
            for (int n = 0; n < 4; ++n) {
                int col = col0 + wn + n * 16 + fr;
                float v = acc[m][n][j] + b1[e * Ddim + col];
                float g = 0.5f * v * (1.0f + erff(v * 0.70710678118654752440f));
                hid[hbase + col] = f2bf(g);
            }
        }
    }
}

// ---------------- Fast GEMM2: out[tok] += p * (hid @ w2t^T + b2) ----------------
__global__ __launch_bounds__(256) void gemm2f_kernel(
    const short* __restrict__ hid, const short* __restrict__ w2t,
    const float* __restrict__ b2, const int* __restrict__ cnt,
    const int* __restrict__ ltok, const float* __restrict__ lw,
    float* __restrict__ out, int CH, int row_base)
{
    constexpr int GX = Hdim / 128;  // 8
    int orig = blockIdx.x + GX * (blockIdx.y + gridDim.y * blockIdx.z);
    int e = orig & 7;
    unsigned rem = (unsigned)orig >> 3;
    int by = rem / GX, bx = rem & (GX - 1);

    int n_e = cnt[e];
    int row0 = row_base + by * 128;
    if (row0 >= n_e) return;
    int col0 = bx * 128;
    int lr0 = row0 - row_base;

    __shared__ short lds[4 * 128 * 64];
    short* As0 = lds;
    short* Bs0 = lds + 8192;
    short* As1 = lds + 16384;
    short* Bs1 = lds + 24576;

    int tid = threadIdx.x;
    int w = tid >> 6, lane = tid & 63;

    const short* aSrc[4]; const short* bSrc[4];
    int dOff[4];
#pragma unroll
    for (int i = 0; i < 4; ++i) {
        int chunk = w * 4 + i;
        int idx = chunk * 64 + lane;
        int row = idx >> 3, q = idx & 7;
        int sc = (q * 16) ^ ((row & 7) << 4);
        aSrc[i] = hid + ((size_t)e * CH + (size_t)(lr0 + row)) * Ddim + (sc >> 1);
        bSrc[i] = w2t + ((size_t)e * Hdim + col0 + row) * Ddim + (sc >> 1);
        dOff[i] = chunk * 512;
    }

    int fr = lane & 15, kg = lane >> 4;
    int wm = (w >> 1) * 64, wn = (w & 1) * 64;

    int pa[4][2], pb[4][2];
#pragma unroll
    for (int m = 0; m < 4; ++m) {
        int row = wm + m * 16 + fr;
        int swz = (row & 7) << 3;
#pragma unroll
        for (int ks = 0; ks < 2; ++ks)
            pa[m][ks] = row * 64 + ((ks * 32 + kg * 8) ^ swz);
    }
#pragma unroll
    for (int n = 0; n < 4; ++n) {
        int row = wn + n * 16 + fr;
        int swz = (row & 7) << 3;
#pragma unroll
        for (int ks = 0; ks < 2; ++ks)
            pb[n][ks] = row * 64 + ((ks * 32 + kg * 8) ^ swz);
    }

    f32x4 acc[4][4];
#pragma unroll
    for (int m = 0; m < 4; ++m)
#pragma unroll
        for (int n = 0; n < 4; ++n) acc[m][n] = (f32x4)0.0f;

    auto stage = [&](short* aB, short* bB) {
#pragma unroll
        for (int i = 0; i < 4; ++i) {
            gl_lds16(aSrc[i], aB + dOff[i]);
            gl_lds16(bSrc[i], bB + dOff[i]);
            aSrc[i] += 64; bSrc[i] += 64;
        }
    };
    auto compute = [&](const short* aB, const short* bB) {
#pragma unroll
        for (int ks = 0; ks < 2; ++ks) {
            bfv8 af[4], bf[4];
#pragma unroll
            for (int m = 0; m < 4; ++m) af[m] = *(const bfv8*)(aB + pa[m][ks]);
#pragma unroll
            for (int n = 0; n < 4; ++n) bf[n] = *(const bfv8*)(bB + pb[n][ks]);
#pragma unroll
            for (int m = 0; m < 4; ++m)
#pragma unroll
                for (int n = 0; n < 4; ++n)
                    acc[m][n] = __builtin_amdgcn_mfma_f32_16x16x32_bf16(af[m], bf[n], acc[m][n], 0, 0, 0);
        }
    };

    constexpr int NK = Ddim / 64;   // 32 (even)
    stage(As0, Bs0);
    SYNC_PREF();
    for (int k = 0; k < NK; k += 2) {
        stage(As1, Bs1);
        compute(As0, Bs0);
        __builtin_amdgcn_sched_barrier(0);
        SYNC_PREF();
        if (k + 2 < NK) stage(As0, Bs0);
        compute(As1, Bs1);
        __builtin_amdgcn_sched_barrier(0);
        SYNC_PREF();
    }

#pragma unroll
    for (int m = 0; m < 4; ++m) {
        int r0r = wm + m * 16 + kg * 4;
#pragma unroll
        for (int j = 0; j < 4; ++j) {
            int gr = row0 + r0r + j;
            if (gr >= n_e) continue;
            int tok = ltok[(size_t)e * Tdim + gr];
            float p = lw[(size_t)e * Tdim + gr];
#pragma unroll
            for (int n = 0; n < 4; ++n) {
                int col = col0 + wn + n * 16 + fr;
                float v = p * (acc[m][n][j] + b2[e * Hdim + col]);
                atomicAdd(&out[(size_t)tok * Hdim + col], v);
            }
        }
    }
}

// ================= Fallback (round-2 verified) kernels =================
#define FBK 64
#define FLDK 72

__global__ __launch_bounds__(256) void gemm1_fb(
    const float* __restrict__ x, const float* __restrict__ w1,
    const float* __restrict__ b1, const int* __restrict__ cnt,
    const int* __restrict__ ltok, short* __restrict__ hid,
    int CH, int row_base)
{
    int e = blockIdx.z;
    int n_e = cnt[e];
    int row0 = row_base + blockIdx.y * 128;
    if (row0 >= n_e) return;
    int col0 = blockIdx.x * 128;

    __shared__ short As[128][FLDK];
    __shared__ short Bs[128][FLDK];

    int tid = threadIdx.x;
    int arow = tid >> 1;
    int akh  = (tid & 1) * 32;
    int gr_a = row0 + arow;
    int tok = ltok[(size_t)e * Tdim + (gr_a < n_e ? gr_a : n_e - 1)];
    const float* xrow = x + (size_t)tok * Hdim + akh;
    int bdg = (tid & 31) * 4;
    int bkg = (tid >> 5) * 4;

    int lane = tid & 63;
    int wid = tid >> 6;
    int wm = (wid >> 1) * 64, wn = (wid & 1) * 64;
    int fr = lane & 15, kg = lane >> 4;

    f32x4 acc[4][4];
#pragma unroll
    for (int m = 0; m < 4; ++m)
#pragma unroll
        for (int n = 0; n < 4; ++n) acc[m][n] = (f32x4)0.0f;

    const float* wB = w1 + (size_t)e * Hdim * Ddim + col0;

    for (int k0 = 0; k0 < Hdim; k0 += FBK) {
#pragma unroll
        for (int i = 0; i < 8; ++i) {
            float4 v = *(const float4*)(xrow + k0 + i * 4);
            s16x4 h; h[0] = f2bf(v.x); h[1] = f2bf(v.y); h[2] = f2bf(v.z); h[3] = f2bf(v.w);
            *(s16x4*)(&As[arow][akh + i * 4]) = h;
        }
#pragma unroll
        for (int r = 0; r < 2; ++r) {
            int kq = bkg + r * 32;
            float4 v0 = *(const float4*)(wB + (size_t)(k0 + kq + 0) * Ddim + bdg);
            float4 v1 = *(const float4*)(wB + (size_t)(k0 + kq + 1) * Ddim + bdg);
            float4 v2 = *(const float4*)(wB + (size_t)(k0 + kq + 2) * Ddim + bdg);
            float4 v3 = *(const float4*)(wB + (size_t)(k0 + kq + 3) * Ddim + bdg);
            const float* p0 = (const float*)&v0; const float* p1 = (const float*)&v1;
            const float* p2 = (const float*)&v2; const float* p3 = (const float*)&v3;
#pragma unroll
            for (int c = 0; c < 4; ++c) {
                s16x4 h; h[0] = f2bf(p0[c]); h[1] = f2bf(p1[c]); h[2] = f2bf(p2[c]); h[3] = f2bf(p3[c]);
                *(s16x4*)(&Bs[bdg + c][kq]) = h;
            }
        }
        __syncthreads();
        bfv8 af[4][2], bfr[4][2];
#pragma unroll
        for (int m = 0; m < 4; ++m)
#pragma unroll
            for (int kk = 0; kk < 2; ++kk)
                af[m][kk] = *(const bfv8*)(&As[wm + m * 16 + fr][kk * 32 + kg * 8]);
#pragma unroll
        for (int n = 0; n < 4; ++n)
#pragma unroll
            for (int kk = 0; kk < 2; ++kk)
                bfr[n][kk] = *(const bfv8*)(&Bs[wn + n * 16 + fr][kk * 32 + kg * 8]);
#pragma unroll
        for (int m = 0; m < 4; ++m)
#pragma unroll
            for (int n = 0; n < 4; ++n) {
                acc[m][n] = __builtin_amdgcn_mfma_f32_16x16x32_bf16(af[m][0], bfr[n][0], acc[m][n], 0, 0, 0);
                acc[m][n] = __builtin_amdgcn_mfma_f32_16x16x32_bf16(af[m][1], bfr[n][1], acc[m][n], 0, 0, 0);
            }
        __syncthreads();
    }

    int lr0 = row0 - row_base;
#pragma unroll
    for (int m = 0; m < 4; ++m) {
        int r0r = wm + m * 16 + kg * 4;
#pragma unroll
        for (int j = 0; j < 4; ++j) {
            int gr = row0 + r0r + j;
            if (gr >= n_e) continue;
            size_t hbase = ((size_t)e * CH + (size_t)(lr0 + r0r + j)) * Ddim;
#pragma unroll
            for (int n = 0; n < 4; ++n) {
                int col = col0 + wn + n * 16 + fr;
                float v = acc[m][n][j] + b1[e * Ddim + col];
                float g = 0.5f * v * (1.0f + erff(v * 0.70710678118654752440f));
                hid[hbase + col] = f2bf(g);
            }
        }
    }
}

__global__ __launch_bounds__(256) void gemm2_fb(
    const short* __restrict__ hid, const float* __restrict__ w2,
    const float* __restrict__ b2, const int* __restrict__ cnt,
    const int* __restrict__ ltok, const float* __restrict__ lw,
    float* __restrict__ out, int CH, int row_base)
{
    int e = blockIdx.z;
    int n_e = cnt[e];
    int row0 = row_base + blockIdx.y * 128;
    if (row0 >= n_e) return;
    int col0 = blockIdx.x * 128;

    __shared__ short As[128][FLDK];
    __shared__ short Bs[128][FLDK];

    int tid = threadIdx.x;
    int arow = tid >> 1;
    int akh  = (tid & 1) * 32;
    const short* hrow = hid + ((size_t)e * CH + (size_t)(row0 - row_base + arow)) * Ddim + akh;
    int bdg = (tid & 31) * 4;
    int bkg = (tid >> 5) * 4;

    int lane = tid & 63;
    int wid = tid >> 6;
    int wm = (wid >> 1) * 64, wn = (wid & 1) * 64;
    int fr = lane & 15, kg = lane >> 4;

    f32x4 acc[4][4];
#pragma unroll
    for (int m = 0; m < 4; ++m)
#pragma unroll
        for (int n = 0; n < 4; ++n) acc[m][n] = (f32x4)0.0f;

    const float* wB = w2 + (size_t)e * Ddim * Hdim + col0;

    for (int k0 = 0; k0 < Ddim; k0 += FBK) {
#pragma unroll
        for (int i = 0; i < 4; ++i) {
            s16x8 v = *(const s16x8*)(hrow + k0 + i * 8);
            *(s16x8*)(&As[arow][akh + i * 8]) = v;
        }
#pragma unroll
        for (int r = 0; r < 2; ++r) {
            int kq = bkg + r * 32;
            float4 v0 = *(const float4*)(wB + (size_t)(k0 + kq + 0) * Hdim + bdg);
            float4 v1 = *(const float4*)(wB + (size_t)(k0 + kq + 1) * Hdim + bdg);
            float4 v2 = *(const float4*)(wB + (size_t)(k0 + kq + 2) * Hdim + bdg);
            float4 v3 = *(const float4*)(wB + (size_t)(k0 + kq + 3) * Hdim + bdg);
            const float* p0 = (const float*)&v0; const float* p1 = (const float*)&v1;
            const float* p2 = (const float*)&v2; const float* p3 = (const float*)&v3;
#pragma unroll
            for (int c = 0; c < 4; ++c) {
                s16x4 h; h[0] = f2bf(p0[c]); h[1] = f2bf(p1[c]); h[2] = f2bf(p2[c]); h[3] = f2bf(p3[c]);
                *(s16x4*)(&Bs[bdg + c][kq]) = h;
            }
        }
        __syncthreads();
        bfv8 af[4][2], bfr[4][2];
#pragma unroll
        for (int m = 0; m < 4; ++m)
#pragma unroll
            for (int kk = 0; kk < 2; ++kk)
                af[m][kk] = *(const bfv8*)(&As[wm + m * 16 + fr][kk * 32 + kg * 8]);
#pragma unroll
        for (int n = 0; n < 4; ++n)
#pragma unroll
            for (int kk = 0; kk < 2; ++kk)
                bfr[n][kk] = *(const bfv8*)(&Bs[wn + n * 16 + fr][kk * 32 + kg * 8]);
#pragma unroll
        for (int m = 0; m < 4; ++m)
#pragma unroll
            for (int n = 0; n < 4; ++n) {
                acc[m][n] = __builtin_amdgcn_mfma_f32_16x16x32_bf16(af[m][0], bfr[n][0], acc[m][n], 0, 0, 0);
                acc[m][n] = __builtin_amdgcn_mfma_f32_16x16x32_bf16(af[m][1], bfr[n][1], acc[m][n], 0, 0, 0);
            }
        __syncthreads();
    }

#pragma unroll
    for (int m = 0; m < 4; ++m) {
        int r0r = wm + m * 16 + kg * 4;
#pragma unroll
        for (int j = 0; j < 4; ++j) {
            int gr = row0 + r0r + j;
            if (gr >= n_e) continue;
            int tok = ltok[(size_t)e * Tdim + gr];
            float p = lw[(size_t)e * Tdim + gr];
#pragma unroll
            for (int n = 0; n < 4; ++n) {
                int col = col0 + wn + n * 16 + fr;
                float v = p * (acc[m][n][j] + b2[e * Hdim + col]);
                atomicAdd(&out[(size_t)tok * Hdim + col], v);
            }
        }
    }
}

// ---------------- Host launch ----------------
extern "C" void kernel_launch(void* const* d_in, const int* in_sizes, int n_in,
                              void* d_out, int out_size, void* d_ws, size_t ws_size,
                              hipStream_t stream)
{
    const float* x  = (const float*)d_in[0];
    const float* gw = (const float*)d_in[1];
    const float* w1 = (const float*)d_in[2];
    const float* b1 = (const float*)d_in[3];
    const float* w2 = (const float*)d_in[4];
    const float* b2 = (const float*)d_in[5];
    float* out = (float*)d_out;

    char* wsb = (char*)d_ws;
    size_t lists = 64 + (size_t)Edim * Tdim * 8;
    size_t xb_sz = (size_t)Tdim * Hdim * 2;
    size_t w_sz  = (size_t)Edim * Hdim * Ddim * 2;

    int CH = 2048;
    while (CH > 256 && lists + xb_sz + 2 * w_sz + (size_t)Edim * CH * Ddim * 2 > ws_size)
        CH >>= 1;
    bool fast = lists + xb_sz + 2 * w_sz + (size_t)Edim * CH * Ddim * 2 <= ws_size;

    int*   cnt  = (int*)wsb;
    float* psum = (float*)(wsb + 32);
    int*   ltok = (int*)(wsb + 64);
    float* lwp  = (float*)(wsb + 64 + (size_t)Edim * Tdim * 4);

    hipMemsetAsync(wsb, 0, 64, stream);
    hipMemsetAsync(d_out, 0, (size_t)out_size * 4, stream);

    if (fast) {
        short* xb  = (short*)(wsb + lists);
        short* w1t = (short*)(wsb + lists + xb_sz);
        short* w2t = (short*)(wsb + lists + xb_sz + w_sz);
        short* hid = (short*)(wsb + lists + xb_sz + 2 * w_sz);

        convx_kernel<<<Tdim * Hdim / 2048, 256, 0, stream>>>(x, xb);
        convt_kernel<<<dim3(Ddim / 64, Hdim / 64, Edim), 256, 0, stream>>>(w1, w1t, Hdim, Ddim);
        convt_kernel<<<dim3(Hdim / 64, Ddim / 64, Edim), 256, 0, stream>>>(w2, w2t, Ddim, Hdim);
        router_kernel<<<64, 256, 0, stream>>>(x, gw, cnt, psum, ltok, lwp);
        aux_kernel<<<1, 64, 0, stream>>>(cnt, psum, out + (size_t)Tdim * Hdim);

        int chunks = Tdim / CH;
        for (int c = 0; c < chunks; ++c) {
            gemm1f_kernel<<<dim3(Ddim / 128, CH / 128, Edim), 256, 0, stream>>>(
                xb, w1t, b1, cnt, ltok, hid, CH, c * CH);
            gemm2f_kernel<<<dim3(Hdim / 128, CH / 128, Edim), 256, 0, stream>>>(
                hid, w2t, b2, cnt, ltok, lwp, out, CH, c * CH);
        }
    } else {
        // round-2 verified path
        size_t fixed = lists;
        short* hid = (short*)(wsb + fixed);
        int CH2 = 2048;
        while (CH2 > 128 && fixed + (size_t)Edim * CH2 * Ddim * 2 > ws_size) CH2 >>= 1;

        router_kernel<<<64, 256, 0, stream>>>(x, gw, cnt, psum, ltok, lwp);
        aux_kernel<<<1, 64, 0, stream>>>(cnt, psum, out + (size_t)Tdim * Hdim);

        int chunks = Tdim / CH2;
        for (int c = 0; c < chunks; ++c) {
            gemm1_fb<<<dim3(Ddim / 128, CH2 / 128, Edim), 256, 0, stream>>>(
                x, w1, b1, cnt, ltok, hid, CH2, c * CH2);
            gemm2_fb<<<dim3(Hdim / 128, CH2 / 128, Edim), 256, 0, stream>>>(
                hid, w2, b2, cnt, ltok, lwp, out, CH2, c * CH2);
        }
    }
}

// Round 5
// 421.783 us; speedup vs baseline: 9.3398x; 1.3931x over previous
//
#include <hip/hip_runtime.h>
#include <hip/hip_bf16.h>
#include <math.h>

#define Bdim 2
#define Sdim 4096
#define Hdim 1024
#define Edim 8
#define Ddim 2048
#define Tdim (Bdim*Sdim)   // 8192 tokens

typedef __attribute__((ext_vector_type(8))) __bf16 bfv8;
typedef __attribute__((ext_vector_type(8))) short s16x8;
typedef __attribute__((ext_vector_type(4))) short s16x4;
typedef __attribute__((ext_vector_type(4))) float f32x4;

__device__ __forceinline__ short f2bf(float f) {
    union { float f; unsigned u; } a; a.f = f;
    unsigned r = (a.u + 0x7fffu + ((a.u >> 16) & 1u)) >> 16;
    return (short)r;
}
__device__ __forceinline__ float bf2f(short s) {
    union { unsigned u; float f; } a; a.u = ((unsigned)(unsigned short)s) << 16;
    return a.f;
}
// tanh-form gelu via exp; |err| < 1e-3 abs (below bf16 GEMM noise)
__device__ __forceinline__ float fgelu(float x) {
    float u = fminf(x * (1.5957691f + 0.07135481f * x * x), 60.0f);
    float t = __expf(u);
    return x * t / (t + 1.0f);
}

typedef const __attribute__((address_space(1))) unsigned int ga_u32;
typedef __attribute__((address_space(3))) unsigned int la_u32;

__device__ __forceinline__ void gl_lds16(const void* g, void* l) {
    __builtin_amdgcn_global_load_lds((ga_u32*)g, (la_u32*)l, 16, 0, 0);
}

#define SYNC_PREF() do {                                   \
    asm volatile("s_waitcnt vmcnt(0)" ::: "memory");       \
    __builtin_amdgcn_s_barrier();                          \
    __builtin_amdgcn_sched_barrier(0);                     \
} while (0)

// ---------------- Router ----------------
// ltok entries encode 2*t + kslot (kslot: 0=top1, 1=top2)
__global__ __launch_bounds__(256) void router_kernel(
    const float* __restrict__ x, const float* __restrict__ gw,
    int* __restrict__ cnt, float* __restrict__ psum,
    int* __restrict__ ltok, float* __restrict__ lw)
{
    __shared__ float gws[Edim * Hdim];
    __shared__ int   lcnt[Edim], gbase[Edim];
    __shared__ int   s_e[256], s_pos[256], s_tok[256];
    __shared__ float s_w[256];
    __shared__ float s_ps[4][8];

    int tid = threadIdx.x;
    for (int i = tid; i < Edim * Hdim / 4; i += 256)
        ((float4*)gws)[i] = ((const float4*)gw)[i];
    if (tid < Edim) lcnt[tid] = 0;
    __syncthreads();

    int wave = tid >> 6, lane = tid & 63;
    double ps = 0.0;

    for (int i = 0; i < 32; ++i) {
        int t = blockIdx.x * 128 + wave * 32 + i;
        double acc[Edim];
#pragma unroll
        for (int e = 0; e < Edim; ++e) acc[e] = 0.0;
#pragma unroll
        for (int kq = 0; kq < 4; ++kq) {
            float4 xv = *(const float4*)(x + (size_t)t * Hdim + kq * 256 + lane * 4);
#pragma unroll
            for (int e = 0; e < Edim; ++e) {
                float4 wv = *(const float4*)(&gws[e * Hdim + kq * 256 + lane * 4]);
                acc[e] += (double)xv.x * wv.x + (double)xv.y * wv.y
                        + (double)xv.z * wv.z + (double)xv.w * wv.w;
            }
        }
#pragma unroll
        for (int e = 0; e < Edim; ++e) {
#pragma unroll
            for (int m = 32; m >= 1; m >>= 1)
                acc[e] += __shfl_xor(acc[e], m, 64);
        }
        int el = lane & 7;
        double v = acc[0];
#pragma unroll
        for (int e = 1; e < Edim; ++e) if (el == e) v = acc[e];
        double mx = v;
#pragma unroll
        for (int m = 1; m < 8; m <<= 1) mx = fmax(mx, __shfl_xor(mx, m, 8));
        double ex = exp(v - mx);
        double sm = ex;
#pragma unroll
        for (int m = 1; m < 8; m <<= 1) sm += __shfl_xor(sm, m, 8);
        double p = ex / sm;
        ps += p;
        double pe[8];
#pragma unroll
        for (int e = 0; e < 8; ++e) pe[e] = __shfl(p, e, 8);
        if (lane == 0) {
            double b1v = -1.0; int e1 = -1;
#pragma unroll
            for (int e = 0; e < 8; ++e) if (pe[e] > b1v) { b1v = pe[e]; e1 = e; }
            double b2v = -1.0; int e2 = -1;
#pragma unroll
            for (int e = 0; e < 8; ++e) if (e != e1 && pe[e] > b2v) { b2v = pe[e]; e2 = e; }
            double inv = 1.0 / (b1v + b2v);
            int lt = wave * 32 + i;
            int p1 = atomicAdd(&lcnt[e1], 1);
            s_e[2*lt] = e1; s_pos[2*lt] = p1; s_tok[2*lt] = 2*t;     s_w[2*lt] = (float)(b1v * inv);
            int p2 = atomicAdd(&lcnt[e2], 1);
            s_e[2*lt+1] = e2; s_pos[2*lt+1] = p2; s_tok[2*lt+1] = 2*t+1; s_w[2*lt+1] = (float)(b2v * inv);
        }
    }
    if (lane < 8) s_ps[wave][lane] = (float)ps;
    __syncthreads();
    if (tid < 8) {
        atomicAdd(&psum[tid], s_ps[0][tid] + s_ps[1][tid] + s_ps[2][tid] + s_ps[3][tid]);
        gbase[tid] = atomicAdd(&cnt[tid], lcnt[tid]);
    }
    __syncthreads();
    {
        int e = s_e[tid];
        int pos = gbase[e] + s_pos[tid];
        ltok[e * Tdim + pos] = s_tok[tid];
        lw[e * Tdim + pos] = s_w[tid];
    }
}

// ---------------- Aux loss + prefix offsets ----------------
__global__ void aux_kernel(const int* __restrict__ cnt,
                           const float* __restrict__ psum,
                           int* __restrict__ eoff,
                           float* __restrict__ out_aux)
{
    if (threadIdx.x == 0 && blockIdx.x == 0) {
        double s = 0.0;
        int run = 0;
        for (int e = 0; e < Edim; ++e) {
            eoff[e] = run;
            run += cnt[e];
            s += ((double)cnt[e] / (double)Bdim) * ((double)psum[e] / (double)Tdim);
        }
        out_aux[0] = (float)((double)Edim * s);
    }
}

// ---------------- Prep: x fp32 -> bf16 ----------------
__global__ __launch_bounds__(256) void convx_kernel(const float* __restrict__ x,
                                                    short* __restrict__ xb)
{
    size_t i = ((size_t)blockIdx.x * 256 + threadIdx.x) * 8;
    float4 a = *(const float4*)(x + i);
    float4 b = *(const float4*)(x + i + 4);
    s16x8 o;
    o[0]=f2bf(a.x); o[1]=f2bf(a.y); o[2]=f2bf(a.z); o[3]=f2bf(a.w);
    o[4]=f2bf(b.x); o[5]=f2bf(b.y); o[6]=f2bf(b.z); o[7]=f2bf(b.w);
    *(s16x8*)(xb + i) = o;
}

// ---------------- Prep: transpose-convert w [E][R][C] fp32 -> wt [E][C][R] bf16 ----------------
__global__ __launch_bounds__(256) void convt_kernel(const float* __restrict__ w,
                                                    short* __restrict__ wt, int R, int C)
{
    int e = blockIdx.z;
    int r0 = blockIdx.y * 64, c0 = blockIdx.x * 64;
    __shared__ short t[64][76];
    int tid = threadIdx.x;
    {
        int r = tid >> 2, cs = (tid & 3) * 16;
        const float* src = w + ((size_t)e * R + r0 + r) * C + c0 + cs;
#pragma unroll
        for (int q = 0; q < 4; ++q) {
            float4 v = *(const float4*)(src + q * 4);
            s16x4 h; h[0]=f2bf(v.x); h[1]=f2bf(v.y); h[2]=f2bf(v.z); h[3]=f2bf(v.w);
            *(s16x4*)(&t[r][cs + q * 4]) = h;
        }
    }
    __syncthreads();
    {
        int c = tid >> 2, rs = (tid & 3) * 16;
        short tmp[16];
#pragma unroll
        for (int j = 0; j < 16; ++j) tmp[j] = t[rs + j][c];
        short* dst = wt + ((size_t)e * C + c0 + c) * R + r0 + rs;
        *(s16x8*)dst = *(s16x8*)tmp;
        *(s16x8*)(dst + 8) = *(s16x8*)(tmp + 8);
    }
}

// ================== 256x256x64, 8 waves, wave-tile 128x64, dbuf 2-phase ==================
// LDS: [A0 32K][B0 32K][A1 32K][B1 32K] bytes = 128 KB

// ---------------- GEMM1: hid[slot] = gelu(Xb[list] @ w1t^T + b1) -> bf16 ----------------
__global__ __launch_bounds__(512, 2) void gemm1n_kernel(
    const short* __restrict__ xb, const short* __restrict__ w1t,
    const float* __restrict__ b1, const int* __restrict__ cnt,
    const int* __restrict__ eoff, const int* __restrict__ ltok,
    short* __restrict__ hid)
{
    constexpr int GXN = Ddim / 256;  // 8
    int id = blockIdx.x;
    int e = id & 7;
    unsigned rem = (unsigned)id >> 3;
    int bx = rem & (GXN - 1);
    int by = rem / GXN;              // 0..31

    int n_e = cnt[e];
    int row0 = by * 256;
    if (row0 >= n_e) return;
    int col0 = bx * 256;
    int slot0 = eoff[e];

    __shared__ short lds[65536];     // 128 KB
    char* ldsb = (char*)lds;

    int tid = threadIdx.x;
    int w = tid >> 6, lane = tid & 63;

    // ---- staging setup: per wave 4 A-chunks + 4 B-chunks per tile ----
    const short* aSrc[4]; const short* bSrc[4];
    int dstOff[4];
#pragma unroll
    for (int i = 0; i < 4; ++i) {
        int chunk = w * 256 + i * 64 + lane;       // 0..2047
        int row = chunk >> 3, q = chunk & 7;
        int sc = (q * 16) ^ ((row & 7) << 4);      // swizzled byte col
        int gr = row0 + row; if (gr > n_e - 1) gr = n_e - 1;
        int tok = ltok[(size_t)e * Tdim + gr] >> 1;
        aSrc[i] = xb + (size_t)tok * Hdim + (sc >> 1);
        bSrc[i] = w1t + ((size_t)e * Ddim + col0 + row) * Hdim + (sc >> 1);
        dstOff[i] = chunk * 16;
    }

    // ---- fragment read pointers ----
    int fr = lane & 15, kg = lane >> 4;
    int wm = (w >> 2) * 128, wn = (w & 3) * 64;
    int swz = (fr & 7) << 3;                        // shorts
    const short* pAk[2]; const short* pBk[2];
#pragma unroll
    for (int ks = 0; ks < 2; ++ks) {
        pAk[ks] = lds + (wm + fr) * 64 + ((ks * 32 + kg * 8) ^ swz);
        pBk[ks] = lds + 16384 + (wn + fr) * 64 + ((ks * 32 + kg * 8) ^ swz);
    }

    f32x4 acc[8][4];
#pragma unroll
    for (int m = 0; m < 8; ++m)
#pragma unroll
        for (int n = 0; n < 4; ++n) acc[m][n] = (f32x4)0.0f;

    auto stage = [&](int bufB) {
#pragma unroll
        for (int i = 0; i < 4; ++i) {
            gl_lds16(aSrc[i], ldsb + bufB + dstOff[i]);
            gl_lds16(bSrc[i], ldsb + bufB + 32768 + dstOff[i]);
            aSrc[i] += 64; bSrc[i] += 64;
        }
    };
    auto compute = [&](int bufS) {
#pragma unroll
        for (int ks = 0; ks < 2; ++ks) {
            bfv8 af[8], bf[4];
#pragma unroll
            for (int n = 0; n < 4; ++n) bf[n] = *(const bfv8*)(pBk[ks] + bufS + n * 1024);
#pragma unroll
            for (int m = 0; m < 8; ++m) af[m] = *(const bfv8*)(pAk[ks] + bufS + m * 1024);
#pragma unroll
            for (int m = 0; m < 8; ++m)
#pragma unroll
                for (int n = 0; n < 4; ++n)
                    acc[m][n] = __builtin_amdgcn_mfma_f32_16x16x32_bf16(af[m], bf[n], acc[m][n], 0, 0, 0);
        }
    };

    constexpr int NK = Hdim / 64;    // 16
    stage(0);
    SYNC_PREF();
    for (int k = 0; k < NK; k += 2) {
        stage(65536);
        compute(0);
        __builtin_amdgcn_sched_barrier(0);
        SYNC_PREF();
        if (k + 2 < NK) stage(0);
        compute(32768);
        __builtin_amdgcn_sched_barrier(0);
        SYNC_PREF();
    }

#pragma unroll
    for (int m = 0; m < 8; ++m) {
        int r0r = wm + m * 16 + kg * 4;
#pragma unroll
        for (int j = 0; j < 4; ++j) {
            int gr = row0 + r0r + j;
            if (gr >= n_e) continue;
            size_t hbase = (size_t)(slot0 + gr) * Ddim;
#pragma unroll
            for (int n = 0; n < 4; ++n) {
                int col = col0 + wn + n * 16 + fr;
                float v = acc[m][n][j] + b1[e * Ddim + col];
                hid[hbase + col] = f2bf(fgelu(v));
            }
        }
    }
}

// ---------------- GEMM2: out2[2t+k] = p * (hid @ w2t^T + b2) -> bf16 ----------------
__global__ __launch_bounds__(512, 2) void gemm2n_kernel(
    const short* __restrict__ hid, const short* __restrict__ w2t,
    const float* __restrict__ b2, const int* __restrict__ cnt,
    const int* __restrict__ eoff, const int* __restrict__ ltok,
    const float* __restrict__ lw, short* __restrict__ out2)
{
    constexpr int GXN = Hdim / 256;  // 4
    int id = blockIdx.x;
    int e = id & 7;
    unsigned rem = (unsigned)id >> 3;
    int bx = rem & (GXN - 1);
    int by = rem / GXN;              // 0..31

    int n_e = cnt[e];
    int row0 = by * 256;
    if (row0 >= n_e) return;
    int col0 = bx * 256;
    int slot0 = eoff[e];

    __shared__ short lds[65536];
    char* ldsb = (char*)lds;

    int tid = threadIdx.x;
    int w = tid >> 6, lane = tid & 63;

    const short* aSrc[4]; const short* bSrc[4];
    int dstOff[4];
#pragma unroll
    for (int i = 0; i < 4; ++i) {
        int chunk = w * 256 + i * 64 + lane;
        int row = chunk >> 3, q = chunk & 7;
        int sc = (q * 16) ^ ((row & 7) << 4);
        int gr = row0 + row; if (gr > n_e - 1) gr = n_e - 1;
        aSrc[i] = hid + (size_t)(slot0 + gr) * Ddim + (sc >> 1);
        bSrc[i] = w2t + ((size_t)e * Hdim + col0 + row) * Ddim + (sc >> 1);
        dstOff[i] = chunk * 16;
    }

    int fr = lane & 15, kg = lane >> 4;
    int wm = (w >> 2) * 128, wn = (w & 3) * 64;
    int swz = (fr & 7) << 3;
    const short* pAk[2]; const short* pBk[2];
#pragma unroll
    for (int ks = 0; ks < 2; ++ks) {
        pAk[ks] = lds + (wm + fr) * 64 + ((ks * 32 + kg * 8) ^ swz);
        pBk[ks] = lds + 16384 + (wn + fr) * 64 + ((ks * 32 + kg * 8) ^ swz);
    }

    f32x4 acc[8][4];
#pragma unroll
    for (int m = 0; m < 8; ++m)
#pragma unroll
        for (int n = 0; n < 4; ++n) acc[m][n] = (f32x4)0.0f;

    auto stage = [&](int bufB) {
#pragma unroll
        for (int i = 0; i < 4; ++i) {
            gl_lds16(aSrc[i], ldsb + bufB + dstOff[i]);
            gl_lds16(bSrc[i], ldsb + bufB + 32768 + dstOff[i]);
            aSrc[i] += 64; bSrc[i] += 64;
        }
    };
    auto compute = [&](int bufS) {
#pragma unroll
        for (int ks = 0; ks < 2; ++ks) {
            bfv8 af[8], bf[4];
#pragma unroll
            for (int n = 0; n < 4; ++n) bf[n] = *(const bfv8*)(pBk[ks] + bufS + n * 1024);
#pragma unroll
            for (int m = 0; m < 8; ++m) af[m] = *(const bfv8*)(pAk[ks] + bufS + m * 1024);
#pragma unroll
            for (int m = 0; m < 8; ++m)
#pragma unroll
                for (int n = 0; n < 4; ++n)
                    acc[m][n] = __builtin_amdgcn_mfma_f32_16x16x32_bf16(af[m], bf[n], acc[m][n], 0, 0, 0);
        }
    };

    constexpr int NK = Ddim / 64;    // 32
    stage(0);
    SYNC_PREF();
    for (int k = 0; k < NK; k += 2) {
        stage(65536);
        compute(0);
        __builtin_amdgcn_sched_barrier(0);
        SYNC_PREF();
        if (k + 2 < NK) stage(0);
        compute(32768);
        __builtin_amdgcn_sched_barrier(0);
        SYNC_PREF();
    }

#pragma unroll
    for (int m = 0; m < 8; ++m) {
        int r0r = wm + m * 16 + kg * 4;
#pragma unroll
        for (int j = 0; j < 4; ++j) {
            int gr = row0 + r0r + j;
            if (gr >= n_e) continue;
            int val = ltok[(size_t)e * Tdim + gr];
            float p = lw[(size_t)e * Tdim + gr];
            size_t obase = (size_t)val * Hdim;
#pragma unroll
            for (int n = 0; n < 4; ++n) {
                int col = col0 + wn + n * 16 + fr;
                float v = p * (acc[m][n][j] + b2[e * Hdim + col]);
                out2[obase + col] = f2bf(v);
            }
        }
    }
}

// ---------------- Combine: out[t] = out2[2t] + out2[2t+1] ----------------
__global__ __launch_bounds__(256) void combine_kernel(const short* __restrict__ out2,
                                                      float* __restrict__ out)
{
    size_t i = ((size_t)blockIdx.x * 256 + threadIdx.x) * 8;
    size_t t = i >> 10;
    int h = (int)(i & 1023);
    s16x8 a = *(const s16x8*)(out2 + (t * 2) * 1024 + h);
    s16x8 b = *(const s16x8*)(out2 + (t * 2 + 1) * 1024 + h);
#pragma unroll
    for (int j = 0; j < 8; ++j)
        out[i + j] = bf2f(a[j]) + bf2f(b[j]);
}

// ================= Fallback (round-2 verified) kernels =================
#define FBK 64
#define FLDK 72

__global__ __launch_bounds__(256) void gemm1_fb(
    const float* __restrict__ x, const float* __restrict__ w1,
    const float* __restrict__ b1, const int* __restrict__ cnt,
    const int* __restrict__ ltok, short* __restrict__ hid,
    int CH, int row_base)
{
    int e = blockIdx.z;
    int n_e = cnt[e];
    int row0 = row_base + blockIdx.y * 128;
    if (row0 >= n_e) return;
    int col0 = blockIdx.x * 128;

    __shared__ short As[128][FLDK];
    __shared__ short Bs[128][FLDK];

    int tid = threadIdx.x;
    int arow = tid >> 1;
    int akh  = (tid & 1) * 32;
    int gr_a = row0 + arow;
    int tok = ltok[(size_t)e * Tdim + (gr_a < n_e ? gr_a : n_e - 1)] >> 1;
    const float* xrow = x + (size_t)tok * Hdim + akh;
    int bdg = (tid & 31) * 4;
    int bkg = (tid >> 5) * 4;

    int lane = tid & 63;
    int wid = tid >> 6;
    int wm = (wid >> 1) * 64, wn = (wid & 1) * 64;
    int fr = lane & 15, kg = lane >> 4;

    f32x4 acc[4][4];
#pragma unroll
    for (int m = 0; m < 4; ++m)
#pragma unroll
        for (int n = 0; n < 4; ++n) acc[m][n] = (f32x4)0.0f;

    const float* wB = w1 + (size_t)e * Hdim * Ddim + col0;

    for (int k0 = 0; k0 < Hdim; k0 += FBK) {
#pragma unroll
        for (int i = 0; i < 8; ++i) {
            float4 v = *(const float4*)(xrow + k0 + i * 4);
            s16x4 h; h[0] = f2bf(v.x); h[1] = f2bf(v.y); h[2] = f2bf(v.z); h[3] = f2bf(v.w);
            *(s16x4*)(&As[arow][akh + i * 4]) = h;
        }
#pragma unroll
        for (int r = 0; r < 2; ++r) {
            int kq = bkg + r * 32;
            float4 v0 = *(const float4*)(wB + (size_t)(k0 + kq + 0) * Ddim + bdg);
            float4 v1 = *(const float4*)(wB + (size_t)(k0 + kq + 1) * Ddim + bdg);
            float4 v2 = *(const float4*)(wB + (size_t)(k0 + kq + 2) * Ddim + bdg);
            float4 v3 = *(const float4*)(wB + (size_t)(k0 + kq + 3) * Ddim + bdg);
            const float* p0 = (const float*)&v0; const float* p1 = (const float*)&v1;
            const float* p2 = (const float*)&v2; const float* p3 = (const float*)&v3;
#pragma unroll
            for (int c = 0; c < 4; ++c) {
                s16x4 h; h[0] = f2bf(p0[c]); h[1] = f2bf(p1[c]); h[2] = f2bf(p2[c]); h[3] = f2bf(p3[c]);
                *(s16x4*)(&Bs[bdg + c][kq]) = h;
            }
        }
        __syncthreads();
        bfv8 af[4][2], bfr[4][2];
#pragma unroll
        for (int m = 0; m < 4; ++m)
#pragma unroll
            for (int kk = 0; kk < 2; ++kk)
                af[m][kk] = *(const bfv8*)(&As[wm + m * 16 + fr][kk * 32 + kg * 8]);
#pragma unroll
        for (int n = 0; n < 4; ++n)
#pragma unroll
            for (int kk = 0; kk < 2; ++kk)
                bfr[n][kk] = *(const bfv8*)(&Bs[wn + n * 16 + fr][kk * 32 + kg * 8]);
#pragma unroll
        for (int m = 0; m < 4; ++m)
#pragma unroll
            for (int n = 0; n < 4; ++n) {
                acc[m][n] = __builtin_amdgcn_mfma_f32_16x16x32_bf16(af[m][0], bfr[n][0], acc[m][n], 0, 0, 0);
                acc[m][n] = __builtin_amdgcn_mfma_f32_16x16x32_bf16(af[m][1], bfr[n][1], acc[m][n], 0, 0, 0);
            }
        __syncthreads();
    }

    int lr0 = row0 - row_base;
#pragma unroll
    for (int m = 0; m < 4; ++m) {
        int r0r = wm + m * 16 + kg * 4;
#pragma unroll
        for (int j = 0; j < 4; ++j) {
            int gr = row0 + r0r + j;
            if (gr >= n_e) continue;
            size_t hbase = ((size_t)e * CH + (size_t)(lr0 + r0r + j)) * Ddim;
#pragma unroll
            for (int n = 0; n < 4; ++n) {
                int col = col0 + wn + n * 16 + fr;
                float v = acc[m][n][j] + b1[e * Ddim + col];
                float g = 0.5f * v * (1.0f + erff(v * 0.70710678118654752440f));
                hid[hbase + col] = f2bf(g);
            }
        }
    }
}

__global__ __launch_bounds__(256) void gemm2_fb(
    const short* __restrict__ hid, const float* __restrict__ w2,
    const float* __restrict__ b2, const int* __restrict__ cnt,
    const int* __restrict__ ltok, const float* __restrict__ lw,
    float* __restrict__ out, int CH, int row_base)
{
    int e = blockIdx.z;
    int n_e = cnt[e];
    int row0 = row_base + blockIdx.y * 128;
    if (row0 >= n_e) return;
    int col0 = blockIdx.x * 128;

    __shared__ short As[128][FLDK];
    __shared__ short Bs[128][FLDK];

    int tid = threadIdx.x;
    int arow = tid >> 1;
    int akh  = (tid & 1) * 32;
    const short* hrow = hid + ((size_t)e * CH + (size_t)(row0 - row_base + arow)) * Ddim + akh;
    int bdg = (tid & 31) * 4;
    int bkg = (tid >> 5) * 4;

    int lane = tid & 63;
    int wid = tid >> 6;
    int wm = (wid >> 1) * 64, wn = (wid & 1) * 64;
    int fr = lane & 15, kg = lane >> 4;

    f32x4 acc[4][4];
#pragma unroll
    for (int m = 0; m < 4; ++m)
#pragma unroll
        for (int n = 0; n < 4; ++n) acc[m][n] = (f32x4)0.0f;

    const float* wB = w2 + (size_t)e * Ddim * Hdim + col0;

    for (int k0 = 0; k0 < Ddim; k0 += FBK) {
#pragma unroll
        for (int i = 0; i < 4; ++i) {
            s16x8 v = *(const s16x8*)(hrow + k0 + i * 8);
            *(s16x8*)(&As[arow][akh + i * 8]) = v;
        }
#pragma unroll
        for (int r = 0; r < 2; ++r) {
            int kq = bkg + r * 32;
            float4 v0 = *(const float4*)(wB + (size_t)(k0 + kq + 0) * Hdim + bdg);
            float4 v1 = *(const float4*)(wB + (size_t)(k0 + kq + 1) * Hdim + bdg);
            float4 v2 = *(const float4*)(wB + (size_t)(k0 + kq + 2) * Hdim + bdg);
            float4 v3 = *(const float4*)(wB + (size_t)(k0 + kq + 3) * Hdim + bdg);
            const float* p0 = (const float*)&v0; const float* p1 = (const float*)&v1;
            const float* p2 = (const float*)&v2; const float* p3 = (const float*)&v3;
#pragma unroll
            for (int c = 0; c < 4; ++c) {
                s16x4 h; h[0] = f2bf(p0[c]); h[1] = f2bf(p1[c]); h[2] = f2bf(p2[c]); h[3] = f2bf(p3[c]);
                *(s16x4*)(&Bs[bdg + c][kq]) = h;
            }
        }
        __syncthreads();
        bfv8 af[4][2], bfr[4][2];
#pragma unroll
        for (int m = 0; m < 4; ++m)
#pragma unroll
            for (int kk = 0; kk < 2; ++kk)
                af[m][kk] = *(const bfv8*)(&As[wm + m * 16 + fr][kk * 32 + kg * 8]);
#pragma unroll
        for (int n = 0; n < 4; ++n)
#pragma unroll
            for (int kk = 0; kk < 2; ++kk)
                bfr[n][kk] = *(const bfv8*)(&Bs[wn + n * 16 + fr][kk * 32 + kg * 8]);
#pragma unroll
        for (int m = 0; m < 4; ++m)
#pragma unroll
            for (int n = 0; n < 4; ++n) {
                acc[m][n] = __builtin_amdgcn_mfma_f32_16x16x32_bf16(af[m][0], bfr[n][0], acc[m][n], 0, 0, 0);
                acc[m][n] = __builtin_amdgcn_mfma_f32_16x16x32_bf16(af[m][1], bfr[n][1], acc[m][n], 0, 0, 0);
            }
        __syncthreads();
    }

#pragma unroll
    for (int m = 0; m < 4; ++m) {
        int r0r = wm + m * 16 + kg * 4;
#pragma unroll
        for (int j = 0; j < 4; ++j) {
            int gr = row0 + r0r + j;
            if (gr >= n_e) continue;
            int tok = ltok[(size_t)e * Tdim + gr] >> 1;
            float p = lw[(size_t)e * Tdim + gr];
#pragma unroll
            for (int n = 0; n < 4; ++n) {
                int col = col0 + wn + n * 16 + fr;
                float v = p * (acc[m][n][j] + b2[e * Hdim + col]);
                atomicAdd(&out[(size_t)tok * Hdim + col], v);
            }
        }
    }
}

// ---------------- Host launch ----------------
extern "C" void kernel_launch(void* const* d_in, const int* in_sizes, int n_in,
                              void* d_out, int out_size, void* d_ws, size_t ws_size,
                              hipStream_t stream)
{
    const float* x  = (const float*)d_in[0];
    const float* gw = (const float*)d_in[1];
    const float* w1 = (const float*)d_in[2];
    const float* b1 = (const float*)d_in[3];
    const float* w2 = (const float*)d_in[4];
    const float* b2 = (const float*)d_in[5];
    float* out = (float*)d_out;

    char* wsb = (char*)d_ws;
    // hdr: cnt[8]@0, psum[8]@32, eoff[8]@64, pad to 128
    int*   cnt  = (int*)wsb;
    float* psum = (float*)(wsb + 32);
    int*   eoff = (int*)(wsb + 64);
    int*   ltok = (int*)(wsb + 128);
    float* lwp  = (float*)(wsb + 128 + (size_t)Edim * Tdim * 4);
    size_t lists_end = 128 + (size_t)Edim * Tdim * 8;

    size_t xb_sz = (size_t)Tdim * Hdim * 2;          // 16 MB
    size_t w1t_sz = (size_t)Edim * Hdim * Ddim * 2;  // 32 MB
    size_t w2t_sz = w1t_sz;                          // 32 MB
    size_t hid_sz = (size_t)(2 * Tdim) * Ddim * 2;   // 64 MB (slot-compact)
    size_t req = lists_end + xb_sz + w1t_sz + w2t_sz + hid_sz;

    hipMemsetAsync(wsb, 0, 128, stream);

    if (req <= ws_size) {
        short* xb   = (short*)(wsb + lists_end);
        short* w1t  = (short*)(wsb + lists_end + xb_sz);
        short* w2t  = (short*)(wsb + lists_end + xb_sz + w1t_sz);
        short* hid  = (short*)(wsb + lists_end + xb_sz + w1t_sz + w2t_sz);
        short* out2 = w1t;   // alias: w1t dead once all gemm1n blocks finish

        convx_kernel<<<Tdim * Hdim / 2048, 256, 0, stream>>>(x, xb);
        convt_kernel<<<dim3(Ddim / 64, Hdim / 64, Edim), 256, 0, stream>>>(w1, w1t, Hdim, Ddim);
        convt_kernel<<<dim3(Hdim / 64, Ddim / 64, Edim), 256, 0, stream>>>(w2, w2t, Ddim, Hdim);
        router_kernel<<<64, 256, 0, stream>>>(x, gw, cnt, psum, ltok, lwp);
        aux_kernel<<<1, 64, 0, stream>>>(cnt, psum, eoff, out + (size_t)Tdim * Hdim);

        gemm1n_kernel<<<(Ddim / 256) * 32 * Edim, 512, 0, stream>>>(
            xb, w1t, b1, cnt, eoff, ltok, hid);
        gemm2n_kernel<<<(Hdim / 256) * 32 * Edim, 512, 0, stream>>>(
            hid, w2t, b2, cnt, eoff, ltok, lwp, out2);
        combine_kernel<<<(size_t)Tdim * Hdim / 2048, 256, 0, stream>>>(out2, out);
    } else {
        // round-2 verified fallback
        short* hid = (short*)(wsb + lists_end);
        int CH2 = 2048;
        while (CH2 > 128 && lists_end + (size_t)Edim * CH2 * Ddim * 2 > ws_size) CH2 >>= 1;

        hipMemsetAsync(d_out, 0, (size_t)out_size * 4, stream);
        router_kernel<<<64, 256, 0, stream>>>(x, gw, cnt, psum, ltok, lwp);
        aux_kernel<<<1, 64, 0, stream>>>(cnt, psum, eoff, out + (size_t)Tdim * Hdim);

        int chunks = Tdim / CH2;
        for (int c = 0; c < chunks; ++c) {
            gemm1_fb<<<dim3(Ddim / 128, CH2 / 128, Edim), 256, 0, stream>>>(
                x, w1, b1, cnt, ltok, hid, CH2, c * CH2);
            gemm2_fb<<<dim3(Hdim / 128, CH2 / 128, Edim), 256, 0, stream>>>(
                hid, w2, b2, cnt, ltok, lwp, out, CH2, c * CH2);
        }
    }
}

// Round 6
// 340.146 us; speedup vs baseline: 11.5814x; 1.2400x over previous
//
#include <hip/hip_runtime.h>
#include <hip/hip_bf16.h>
#include <math.h>

#define Bdim 2
#define Sdim 4096
#define Hdim 1024
#define Edim 8
#define Ddim 2048
#define Tdim (Bdim*Sdim)   // 8192 tokens

typedef __attribute__((ext_vector_type(8))) __bf16 bfv8;
typedef __attribute__((ext_vector_type(8))) short s16x8;
typedef __attribute__((ext_vector_type(4))) short s16x4;
typedef __attribute__((ext_vector_type(4))) float f32x4;

__device__ __forceinline__ short f2bf(float f) {
    union { float f; unsigned u; } a; a.f = f;
    unsigned r = (a.u + 0x7fffu + ((a.u >> 16) & 1u)) >> 16;
    return (short)r;
}
__device__ __forceinline__ float bf2f(short s) {
    union { unsigned u; float f; } a; a.u = ((unsigned)(unsigned short)s) << 16;
    return a.f;
}
// tanh-form gelu via exp; |err| < 1e-3 abs (below bf16 GEMM noise)
__device__ __forceinline__ float fgelu(float x) {
    float u = fminf(x * (1.5957691f + 0.07135481f * x * x), 60.0f);
    float t = __expf(u);
    return x * t / (t + 1.0f);
}

typedef const __attribute__((address_space(1))) unsigned int ga_u32;
typedef __attribute__((address_space(3))) unsigned int la_u32;

__device__ __forceinline__ void gl_lds16(const void* g, void* l) {
    __builtin_amdgcn_global_load_lds((ga_u32*)g, (la_u32*)l, 16, 0, 0);
}

#define SYNC_PREF() do {                                   \
    asm volatile("s_waitcnt vmcnt(0)" ::: "memory");       \
    __builtin_amdgcn_s_barrier();                          \
    __builtin_amdgcn_sched_barrier(0);                     \
} while (0)

// ---------------- Router: 512 blocks x 256 thr; wave handles 4 tokens ----------------
// ltok entries encode 2*t + kslot. Also emits xb (bf16 copy of x) when xb != nullptr.
__global__ __launch_bounds__(256) void router_kernel(
    const float* __restrict__ x, const float* __restrict__ gw,
    int* __restrict__ cnt, float* __restrict__ psum,
    int* __restrict__ ltok, float* __restrict__ lw,
    short* __restrict__ xb)
{
    __shared__ float gws[Edim * Hdim];          // 32 KB
    __shared__ int   lcnt[Edim], gbase[Edim];
    __shared__ int   s_e[32], s_pos[32], s_tok[32];
    __shared__ float s_w[32];
    __shared__ float s_ps[4][8];

    int tid = threadIdx.x;
    for (int i = tid; i < Edim * Hdim / 4; i += 256)
        ((float4*)gws)[i] = ((const float4*)gw)[i];
    if (tid < Edim) lcnt[tid] = 0;
    __syncthreads();

    int wave = tid >> 6, lane = tid & 63;
    float ps = 0.f;

    for (int i = 0; i < 4; ++i) {
        int t = blockIdx.x * 16 + wave * 4 + i;
        double acc[Edim];
#pragma unroll
        for (int e = 0; e < Edim; ++e) acc[e] = 0.0;
#pragma unroll
        for (int kq = 0; kq < 4; ++kq) {
            float4 xv = *(const float4*)(x + (size_t)t * Hdim + kq * 256 + lane * 4);
            if (xb) {
                s16x4 h; h[0]=f2bf(xv.x); h[1]=f2bf(xv.y); h[2]=f2bf(xv.z); h[3]=f2bf(xv.w);
                *(s16x4*)(xb + (size_t)t * Hdim + kq * 256 + lane * 4) = h;
            }
#pragma unroll
            for (int e = 0; e < Edim; ++e) {
                float4 wv = *(const float4*)(&gws[e * Hdim + kq * 256 + lane * 4]);
                acc[e] += (double)xv.x * wv.x + (double)xv.y * wv.y
                        + (double)xv.z * wv.z + (double)xv.w * wv.w;
            }
        }
        // stage A: reduce dims within each 8-lane group, all 8 experts
#pragma unroll
        for (int e = 0; e < Edim; ++e) {
            acc[e] += __shfl_xor(acc[e], 1, 64);
            acc[e] += __shfl_xor(acc[e], 2, 64);
            acc[e] += __shfl_xor(acc[e], 4, 64);
        }
        // select own expert, stage B: reduce across groups (same expert)
        int el = lane & 7;
        double v = acc[0];
#pragma unroll
        for (int e = 1; e < Edim; ++e) if (el == e) v = acc[e];
        v += __shfl_xor(v, 8, 64);
        v += __shfl_xor(v, 16, 64);
        v += __shfl_xor(v, 32, 64);
        // v = exact fp64 logit of expert el, replicated in every 8-lane group
        double mx = v;
        mx = fmax(mx, __shfl_xor(mx, 1, 64));
        mx = fmax(mx, __shfl_xor(mx, 2, 64));
        mx = fmax(mx, __shfl_xor(mx, 4, 64));
        float ex = __expf((float)(v - mx));
        float sm = ex;
        sm += __shfl_xor(sm, 1, 64);
        sm += __shfl_xor(sm, 2, 64);
        sm += __shfl_xor(sm, 4, 64);
        ps += ex / sm;
        // top-2 selection on exact fp64 logits (ties -> lower index)
        double le[8];
#pragma unroll
        for (int e = 0; e < 8; ++e) le[e] = __shfl(v, e, 8);
        if (lane == 0) {
            int e1 = 0;
#pragma unroll
            for (int e = 1; e < 8; ++e) if (le[e] > le[e1]) e1 = e;
            int e2 = -1;
#pragma unroll
            for (int e = 0; e < 8; ++e) {
                if (e == e1) continue;
                if (e2 < 0 || le[e] > le[e2]) e2 = e;
            }
            float r = __expf((float)(le[e2] - le[e1]));   // p2/p1
            float w1v = 1.0f / (1.0f + r);
            int lt = (wave * 4 + i) * 2;
            int p1 = atomicAdd(&lcnt[e1], 1);
            s_e[lt] = e1; s_pos[lt] = p1; s_tok[lt] = 2*t;     s_w[lt] = w1v;
            int p2 = atomicAdd(&lcnt[e2], 1);
            s_e[lt+1] = e2; s_pos[lt+1] = p2; s_tok[lt+1] = 2*t+1; s_w[lt+1] = 1.0f - w1v;
        }
    }
    if (lane < 8) s_ps[wave][lane] = ps;
    __syncthreads();
    if (tid < 8) {
        atomicAdd(&psum[tid], s_ps[0][tid] + s_ps[1][tid] + s_ps[2][tid] + s_ps[3][tid]);
        gbase[tid] = atomicAdd(&cnt[tid], lcnt[tid]);
    }
    __syncthreads();
    if (tid < 32) {
        int e = s_e[tid];
        int pos = gbase[e] + s_pos[tid];
        ltok[e * Tdim + pos] = s_tok[tid];
        lw[e * Tdim + pos] = s_w[tid];
    }
}

// ---------------- Aux loss + prefix offsets ----------------
__global__ void aux_kernel(const int* __restrict__ cnt,
                           const float* __restrict__ psum,
                           int* __restrict__ eoff,
                           float* __restrict__ out_aux)
{
    if (threadIdx.x == 0 && blockIdx.x == 0) {
        double s = 0.0;
        int run = 0;
        for (int e = 0; e < Edim; ++e) {
            eoff[e] = run;
            run += cnt[e];
            s += ((double)cnt[e] / (double)Bdim) * ((double)psum[e] / (double)Tdim);
        }
        out_aux[0] = (float)((double)Edim * s);
    }
}

// ---------------- Prep: transpose-convert w [E][R][C] fp32 -> wt [E][C][R] bf16 ----------------
__global__ __launch_bounds__(256) void convt_kernel(const float* __restrict__ w,
                                                    short* __restrict__ wt, int R, int C)
{
    int e = blockIdx.z;
    int r0 = blockIdx.y * 64, c0 = blockIdx.x * 64;
    __shared__ short t[64][76];
    int tid = threadIdx.x;
    {
        int r = tid >> 2, cs = (tid & 3) * 16;
        const float* src = w + ((size_t)e * R + r0 + r) * C + c0 + cs;
#pragma unroll
        for (int q = 0; q < 4; ++q) {
            float4 v = *(const float4*)(src + q * 4);
            s16x4 h; h[0]=f2bf(v.x); h[1]=f2bf(v.y); h[2]=f2bf(v.z); h[3]=f2bf(v.w);
            *(s16x4*)(&t[r][cs + q * 4]) = h;
        }
    }
    __syncthreads();
    {
        int c = tid >> 2, rs = (tid & 3) * 16;
        short tmp[16];
#pragma unroll
        for (int j = 0; j < 16; ++j) tmp[j] = t[rs + j][c];
        short* dst = wt + ((size_t)e * C + c0 + c) * R + r0 + rs;
        *(s16x8*)dst = *(s16x8*)tmp;
        *(s16x8*)(dst + 8) = *(s16x8*)(tmp + 8);
    }
}

// ================== 256x256x64, 8 waves, wave-tile 128x64, dbuf 2-phase ==================

// ---------------- GEMM1: hid[slot] = gelu(Xb[list] @ w1t^T + b1) -> bf16 ----------------
__global__ __launch_bounds__(512, 2) void gemm1n_kernel(
    const short* __restrict__ xb, const short* __restrict__ w1t,
    const float* __restrict__ b1, const int* __restrict__ cnt,
    const int* __restrict__ eoff, const int* __restrict__ ltok,
    short* __restrict__ hid)
{
    constexpr int GXN = Ddim / 256;  // 8
    int id = blockIdx.x;
    int e = id & 7;
    unsigned rem = (unsigned)id >> 3;
    int bx = rem & (GXN - 1);
    int by = rem / GXN;              // 0..31

    int n_e = cnt[e];
    int row0 = by * 256;
    if (row0 >= n_e) return;
    int col0 = bx * 256;
    int slot0 = eoff[e];

    __shared__ short lds[65536];     // 128 KB
    char* ldsb = (char*)lds;

    int tid = threadIdx.x;
    int w = tid >> 6, lane = tid & 63;

    const short* aSrc[4]; const short* bSrc[4];
    int dstOff[4];
#pragma unroll
    for (int i = 0; i < 4; ++i) {
        int chunk = w * 256 + i * 64 + lane;       // 0..2047
        int row = chunk >> 3, q = chunk & 7;
        int sc = (q * 16) ^ ((row & 7) << 4);      // swizzled byte col
        int gr = row0 + row; if (gr > n_e - 1) gr = n_e - 1;
        int tok = ltok[(size_t)e * Tdim + gr] >> 1;
        aSrc[i] = xb + (size_t)tok * Hdim + (sc >> 1);
        bSrc[i] = w1t + ((size_t)e * Ddim + col0 + row) * Hdim + (sc >> 1);
        dstOff[i] = chunk * 16;
    }

    int fr = lane & 15, kg = lane >> 4;
    int wm = (w >> 2) * 128, wn = (w & 3) * 64;
    int swz = (fr & 7) << 3;
    const short* pAk[2]; const short* pBk[2];
#pragma unroll
    for (int ks = 0; ks < 2; ++ks) {
        pAk[ks] = lds + (wm + fr) * 64 + ((ks * 32 + kg * 8) ^ swz);
        pBk[ks] = lds + 16384 + (wn + fr) * 64 + ((ks * 32 + kg * 8) ^ swz);
    }

    f32x4 acc[8][4];
#pragma unroll
    for (int m = 0; m < 8; ++m)
#pragma unroll
        for (int n = 0; n < 4; ++n) acc[m][n] = (f32x4)0.0f;

    auto stage = [&](int bufB) {
#pragma unroll
        for (int i = 0; i < 4; ++i) {
            gl_lds16(aSrc[i], ldsb + bufB + dstOff[i]);
            gl_lds16(bSrc[i], ldsb + bufB + 32768 + dstOff[i]);
            aSrc[i] += 64; bSrc[i] += 64;
        }
    };
    auto compute = [&](int bufS) {
#pragma unroll
        for (int ks = 0; ks < 2; ++ks) {
            bfv8 af[8], bf[4];
#pragma unroll
            for (int n = 0; n < 4; ++n) bf[n] = *(const bfv8*)(pBk[ks] + bufS + n * 1024);
#pragma unroll
            for (int m = 0; m < 8; ++m) af[m] = *(const bfv8*)(pAk[ks] + bufS + m * 1024);
#pragma unroll
            for (int m = 0; m < 8; ++m)
#pragma unroll
                for (int n = 0; n < 4; ++n)
                    acc[m][n] = __builtin_amdgcn_mfma_f32_16x16x32_bf16(af[m], bf[n], acc[m][n], 0, 0, 0);
        }
    };

    constexpr int NK = Hdim / 64;    // 16
    stage(0);
    SYNC_PREF();
    for (int k = 0; k < NK; k += 2) {
        stage(65536);
        compute(0);
        __builtin_amdgcn_sched_barrier(0);
        SYNC_PREF();
        if (k + 2 < NK) stage(0);
        compute(32768);
        __builtin_amdgcn_sched_barrier(0);
        SYNC_PREF();
    }

#pragma unroll
    for (int m = 0; m < 8; ++m) {
        int r0r = wm + m * 16 + kg * 4;
#pragma unroll
        for (int j = 0; j < 4; ++j) {
            int gr = row0 + r0r + j;
            if (gr >= n_e) continue;
            size_t hbase = (size_t)(slot0 + gr) * Ddim;
#pragma unroll
            for (int n = 0; n < 4; ++n) {
                int col = col0 + wn + n * 16 + fr;
                float v = acc[m][n][j] + b1[e * Ddim + col];
                hid[hbase + col] = f2bf(fgelu(v));
            }
        }
    }
}

// ---------------- GEMM2: out2[2t+k] = p * (hid @ w2t^T + b2) -> bf16 ----------------
__global__ __launch_bounds__(512, 2) void gemm2n_kernel(
    const short* __restrict__ hid, const short* __restrict__ w2t,
    const float* __restrict__ b2, const int* __restrict__ cnt,
    const int* __restrict__ eoff, const int* __restrict__ ltok,
    const float* __restrict__ lw, short* __restrict__ out2)
{
    constexpr int GXN = Hdim / 256;  // 4
    int id = blockIdx.x;
    int e = id & 7;
    unsigned rem = (unsigned)id >> 3;
    int bx = rem & (GXN - 1);
    int by = rem / GXN;              // 0..31

    int n_e = cnt[e];
    int row0 = by * 256;
    if (row0 >= n_e) return;
    int col0 = bx * 256;
    int slot0 = eoff[e];

    __shared__ short lds[65536];
    char* ldsb = (char*)lds;

    int tid = threadIdx.x;
    int w = tid >> 6, lane = tid & 63;

    const short* aSrc[4]; const short* bSrc[4];
    int dstOff[4];
#pragma unroll
    for (int i = 0; i < 4; ++i) {
        int chunk = w * 256 + i * 64 + lane;
        int row = chunk >> 3, q = chunk & 7;
        int sc = (q * 16) ^ ((row & 7) << 4);
        int gr = row0 + row; if (gr > n_e - 1) gr = n_e - 1;
        aSrc[i] = hid + (size_t)(slot0 + gr) * Ddim + (sc >> 1);
        bSrc[i] = w2t + ((size_t)e * Hdim + col0 + row) * Ddim + (sc >> 1);
        dstOff[i] = chunk * 16;
    }

    int fr = lane & 15, kg = lane >> 4;
    int wm = (w >> 2) * 128, wn = (w & 3) * 64;
    int swz = (fr & 7) << 3;
    const short* pAk[2]; const short* pBk[2];
#pragma unroll
    for (int ks = 0; ks < 2; ++ks) {
        pAk[ks] = lds + (wm + fr) * 64 + ((ks * 32 + kg * 8) ^ swz);
        pBk[ks] = lds + 16384 + (wn + fr) * 64 + ((ks * 32 + kg * 8) ^ swz);
    }

    f32x4 acc[8][4];
#pragma unroll
    for (int m = 0; m < 8; ++m)
#pragma unroll
        for (int n = 0; n < 4; ++n) acc[m][n] = (f32x4)0.0f;

    auto stage = [&](int bufB) {
#pragma unroll
        for (int i = 0; i < 4; ++i) {
            gl_lds16(aSrc[i], ldsb + bufB + dstOff[i]);
            gl_lds16(bSrc[i], ldsb + bufB + 32768 + dstOff[i]);
            aSrc[i] += 64; bSrc[i] += 64;
        }
    };
    auto compute = [&](int bufS) {
#pragma unroll
        for (int ks = 0; ks < 2; ++ks) {
            bfv8 af[8], bf[4];
#pragma unroll
            for (int n = 0; n < 4; ++n) bf[n] = *(const bfv8*)(pBk[ks] + bufS + n * 1024);
#pragma unroll
            for (int m = 0; m < 8; ++m) af[m] = *(const bfv8*)(pAk[ks] + bufS + m * 1024);
#pragma unroll
            for (int m = 0; m < 8; ++m)
#pragma unroll
                for (int n = 0; n < 4; ++n)
                    acc[m][n] = __builtin_amdgcn_mfma_f32_16x16x32_bf16(af[m], bf[n], acc[m][n], 0, 0, 0);
        }
    };

    constexpr int NK = Ddim / 64;    // 32
    stage(0);
    SYNC_PREF();
    for (int k = 0; k < NK; k += 2) {
        stage(65536);
        compute(0);
        __builtin_amdgcn_sched_barrier(0);
        SYNC_PREF();
        if (k + 2 < NK) stage(0);
        compute(32768);
        __builtin_amdgcn_sched_barrier(0);
        SYNC_PREF();
    }

#pragma unroll
    for (int m = 0; m < 8; ++m) {
        int r0r = wm + m * 16 + kg * 4;
#pragma unroll
        for (int j = 0; j < 4; ++j) {
            int gr = row0 + r0r + j;
            if (gr >= n_e) continue;
            int val = ltok[(size_t)e * Tdim + gr];
            float p = lw[(size_t)e * Tdim + gr];
            size_t obase = (size_t)val * Hdim;
#pragma unroll
            for (int n = 0; n < 4; ++n) {
                int col = col0 + wn + n * 16 + fr;
                float v = p * (acc[m][n][j] + b2[e * Hdim + col]);
                out2[obase + col] = f2bf(v);
            }
        }
    }
}

// ---------------- Combine: out[t] = out2[2t] + out2[2t+1] ----------------
__global__ __launch_bounds__(256) void combine_kernel(const short* __restrict__ out2,
                                                      float* __restrict__ out)
{
    size_t i = ((size_t)blockIdx.x * 256 + threadIdx.x) * 8;
    size_t t = i >> 10;
    int h = (int)(i & 1023);
    s16x8 a = *(const s16x8*)(out2 + (t * 2) * 1024 + h);
    s16x8 b = *(const s16x8*)(out2 + (t * 2 + 1) * 1024 + h);
#pragma unroll
    for (int j = 0; j < 8; ++j)
        out[i + j] = bf2f(a[j]) + bf2f(b[j]);
}

// ================= Fallback (round-2 verified) kernels =================
#define FBK 64
#define FLDK 72

__global__ __launch_bounds__(256) void gemm1_fb(
    const float* __restrict__ x, const float* __restrict__ w1,
    const float* __restrict__ b1, const int* __restrict__ cnt,
    const int* __restrict__ ltok, short* __restrict__ hid,
    int CH, int row_base)
{
    int e = blockIdx.z;
    int n_e = cnt[e];
    int row0 = row_base + blockIdx.y * 128;
    if (row0 >= n_e) return;
    int col0 = blockIdx.x * 128;

    __shared__ short As[128][FLDK];
    __shared__ short Bs[128][FLDK];

    int tid = threadIdx.x;
    int arow = tid >> 1;
    int akh  = (tid & 1) * 32;
    int gr_a = row0 + arow;
    int tok = ltok[(size_t)e * Tdim + (gr_a < n_e ? gr_a : n_e - 1)] >> 1;
    const float* xrow = x + (size_t)tok * Hdim + akh;
    int bdg = (tid & 31) * 4;
    int bkg = (tid >> 5) * 4;

    int lane = tid & 63;
    int wid = tid >> 6;
    int wm = (wid >> 1) * 64, wn = (wid & 1) * 64;
    int fr = lane & 15, kg = lane >> 4;

    f32x4 acc[4][4];
#pragma unroll
    for (int m = 0; m < 4; ++m)
#pragma unroll
        for (int n = 0; n < 4; ++n) acc[m][n] = (f32x4)0.0f;

    const float* wB = w1 + (size_t)e * Hdim * Ddim + col0;

    for (int k0 = 0; k0 < Hdim; k0 += FBK) {
#pragma unroll
        for (int i = 0; i < 8; ++i) {
            float4 v = *(const float4*)(xrow + k0 + i * 4);
            s16x4 h; h[0] = f2bf(v.x); h[1] = f2bf(v.y); h[2] = f2bf(v.z); h[3] = f2bf(v.w);
            *(s16x4*)(&As[arow][akh + i * 4]) = h;
        }
#pragma unroll
        for (int r = 0; r < 2; ++r) {
            int kq = bkg + r * 32;
            float4 v0 = *(const float4*)(wB + (size_t)(k0 + kq + 0) * Ddim + bdg);
            float4 v1 = *(const float4*)(wB + (size_t)(k0 + kq + 1) * Ddim + bdg);
            float4 v2 = *(const float4*)(wB + (size_t)(k0 + kq + 2) * Ddim + bdg);
            float4 v3 = *(const float4*)(wB + (size_t)(k0 + kq + 3) * Ddim + bdg);
            const float* p0 = (const float*)&v0; const float* p1 = (const float*)&v1;
            const float* p2 = (const float*)&v2; const float* p3 = (const float*)&v3;
#pragma unroll
            for (int c = 0; c < 4; ++c) {
                s16x4 h; h[0] = f2bf(p0[c]); h[1] = f2bf(p1[c]); h[2] = f2bf(p2[c]); h[3] = f2bf(p3[c]);
                *(s16x4*)(&Bs[bdg + c][kq]) = h;
            }
        }
        __syncthreads();
        bfv8 af[4][2], bfr[4][2];
#pragma unroll
        for (int m = 0; m < 4; ++m)
#pragma unroll
            for (int kk = 0; kk < 2; ++kk)
                af[m][kk] = *(const bfv8*)(&As[wm + m * 16 + fr][kk * 32 + kg * 8]);
#pragma unroll
        for (int n = 0; n < 4; ++n)
#pragma unroll
            for (int kk = 0; kk < 2; ++kk)
                bfr[n][kk] = *(const bfv8*)(&Bs[wn + n * 16 + fr][kk * 32 + kg * 8]);
#pragma unroll
        for (int m = 0; m < 4; ++m)
#pragma unroll
            for (int n = 0; n < 4; ++n) {
                acc[m][n] = __builtin_amdgcn_mfma_f32_16x16x32_bf16(af[m][0], bfr[n][0], acc[m][n], 0, 0, 0);
                acc[m][n] = __builtin_amdgcn_mfma_f32_16x16x32_bf16(af[m][1], bfr[n][1], acc[m][n], 0, 0, 0);
            }
        __syncthreads();
    }

    int lr0 = row0 - row_base;
#pragma unroll
    for (int m = 0; m < 4; ++m) {
        int r0r = wm + m * 16 + kg * 4;
#pragma unroll
        for (int j = 0; j < 4; ++j) {
            int gr = row0 + r0r + j;
            if (gr >= n_e) continue;
            size_t hbase = ((size_t)e * CH + (size_t)(lr0 + r0r + j)) * Ddim;
#pragma unroll
            for (int n = 0; n < 4; ++n) {
                int col = col0 + wn + n * 16 + fr;
                float v = acc[m][n][j] + b1[e * Ddim + col];
                float g = 0.5f * v * (1.0f + erff(v * 0.70710678118654752440f));
                hid[hbase + col] = f2bf(g);
            }
        }
    }
}

__global__ __launch_bounds__(256) void gemm2_fb(
    const short* __restrict__ hid, const float* __restrict__ w2,
    const float* __restrict__ b2, const int* __restrict__ cnt,
    const int* __restrict__ ltok, const float* __restrict__ lw,
    float* __restrict__ out, int CH, int row_base)
{
    int e = blockIdx.z;
    int n_e = cnt[e];
    int row0 = row_base + blockIdx.y * 128;
    if (row0 >= n_e) return;
    int col0 = blockIdx.x * 128;

    __shared__ short As[128][FLDK];
    __shared__ short Bs[128][FLDK];

    int tid = threadIdx.x;
    int arow = tid >> 1;
    int akh  = (tid & 1) * 32;
    const short* hrow = hid + ((size_t)e * CH + (size_t)(row0 - row_base + arow)) * Ddim + akh;
    int bdg = (tid & 31) * 4;
    int bkg = (tid >> 5) * 4;

    int lane = tid & 63;
    int wid = tid >> 6;
    int wm = (wid >> 1) * 64, wn = (wid & 1) * 64;
    int fr = lane & 15, kg = lane >> 4;

    f32x4 acc[4][4];
#pragma unroll
    for (int m = 0; m < 4; ++m)
#pragma unroll
        for (int n = 0; n < 4; ++n) acc[m][n] = (f32x4)0.0f;

    const float* wB = w2 + (size_t)e * Ddim * Hdim + col0;

    for (int k0 = 0; k0 < Ddim; k0 += FBK) {
#pragma unroll
        for (int i = 0; i < 4; ++i) {
            s16x8 v = *(const s16x8*)(hrow + k0 + i * 8);
            *(s16x8*)(&As[arow][akh + i * 8]) = v;
        }
#pragma unroll
        for (int r = 0; r < 2; ++r) {
            int kq = bkg + r * 32;
            float4 v0 = *(const float4*)(wB + (size_t)(k0 + kq + 0) * Hdim + bdg);
            float4 v1 = *(const float4*)(wB + (size_t)(k0 + kq + 1) * Hdim + bdg);
            float4 v2 = *(const float4*)(wB + (size_t)(k0 + kq + 2) * Hdim + bdg);
            float4 v3 = *(const float4*)(wB + (size_t)(k0 + kq + 3) * Hdim + bdg);
            const float* p0 = (const float*)&v0; const float* p1 = (const float*)&v1;
            const float* p2 = (const float*)&v2; const float* p3 = (const float*)&v3;
#pragma unroll
            for (int c = 0; c < 4; ++c) {
                s16x4 h; h[0] = f2bf(p0[c]); h[1] = f2bf(p1[c]); h[2] = f2bf(p2[c]); h[3] = f2bf(p3[c]);
                *(s16x4*)(&Bs[bdg + c][kq]) = h;
            }
        }
        __syncthreads();
        bfv8 af[4][2], bfr[4][2];
#pragma unroll
        for (int m = 0; m < 4; ++m)
#pragma unroll
            for (int kk = 0; kk < 2; ++kk)
                af[m][kk] = *(const bfv8*)(&As[wm + m * 16 + fr][kk * 32 + kg * 8]);
#pragma unroll
        for (int n = 0; n < 4; ++n)
#pragma unroll
            for (int kk = 0; kk < 2; ++kk)
                bfr[n][kk] = *(const bfv8*)(&Bs[wn + n * 16 + fr][kk * 32 + kg * 8]);
#pragma unroll
        for (int m = 0; m < 4; ++m)
#pragma unroll
            for (int n = 0; n < 4; ++n) {
                acc[m][n] = __builtin_amdgcn_mfma_f32_16x16x32_bf16(af[m][0], bfr[n][0], acc[m][n], 0, 0, 0);
                acc[m][n] = __builtin_amdgcn_mfma_f32_16x16x32_bf16(af[m][1], bfr[n][1], acc[m][n], 0, 0, 0);
            }
        __syncthreads();
    }

#pragma unroll
    for (int m = 0; m < 4; ++m) {
        int r0r = wm + m * 16 + kg * 4;
#pragma unroll
        for (int j = 0; j < 4; ++j) {
            int gr = row0 + r0r + j;
            if (gr >= n_e) continue;
            int tok = ltok[(size_t)e * Tdim + gr] >> 1;
            float p = lw[(size_t)e * Tdim + gr];
#pragma unroll
            for (int n = 0; n < 4; ++n) {
                int col = col0 + wn + n * 16 + fr;
                float v = p * (acc[m][n][j] + b2[e * Hdim + col]);
                atomicAdd(&out[(size_t)tok * Hdim + col], v);
            }
        }
    }
}

// ---------------- Host launch ----------------
extern "C" void kernel_launch(void* const* d_in, const int* in_sizes, int n_in,
                              void* d_out, int out_size, void* d_ws, size_t ws_size,
                              hipStream_t stream)
{
    const float* x  = (const float*)d_in[0];
    const float* gw = (const float*)d_in[1];
    const float* w1 = (const float*)d_in[2];
    const float* b1 = (const float*)d_in[3];
    const float* w2 = (const float*)d_in[4];
    const float* b2 = (const float*)d_in[5];
    float* out = (float*)d_out;

    char* wsb = (char*)d_ws;
    // hdr: cnt[8]@0, psum[8]@32, eoff[8]@64, pad to 128
    int*   cnt  = (int*)wsb;
    float* psum = (float*)(wsb + 32);
    int*   eoff = (int*)(wsb + 64);
    int*   ltok = (int*)(wsb + 128);
    float* lwp  = (float*)(wsb + 128 + (size_t)Edim * Tdim * 4);
    size_t lists_end = 128 + (size_t)Edim * Tdim * 8;

    size_t xb_sz = (size_t)Tdim * Hdim * 2;          // 16 MB
    size_t w1t_sz = (size_t)Edim * Hdim * Ddim * 2;  // 32 MB
    size_t w2t_sz = w1t_sz;                          // 32 MB
    size_t hid_sz = (size_t)(2 * Tdim) * Ddim * 2;   // 64 MB (slot-compact)
    size_t req = lists_end + xb_sz + w1t_sz + w2t_sz + hid_sz;

    hipMemsetAsync(wsb, 0, 128, stream);

    if (req <= ws_size) {
        short* xb   = (short*)(wsb + lists_end);
        short* w1t  = (short*)(wsb + lists_end + xb_sz);
        short* w2t  = (short*)(wsb + lists_end + xb_sz + w1t_sz);
        short* hid  = (short*)(wsb + lists_end + xb_sz + w1t_sz + w2t_sz);
        short* out2 = w1t;   // alias: w1t dead once all gemm1n blocks finish

        convt_kernel<<<dim3(Ddim / 64, Hdim / 64, Edim), 256, 0, stream>>>(w1, w1t, Hdim, Ddim);
        convt_kernel<<<dim3(Hdim / 64, Ddim / 64, Edim), 256, 0, stream>>>(w2, w2t, Ddim, Hdim);
        router_kernel<<<Tdim / 16, 256, 0, stream>>>(x, gw, cnt, psum, ltok, lwp, xb);
        aux_kernel<<<1, 64, 0, stream>>>(cnt, psum, eoff, out + (size_t)Tdim * Hdim);

        gemm1n_kernel<<<(Ddim / 256) * 32 * Edim, 512, 0, stream>>>(
            xb, w1t, b1, cnt, eoff, ltok, hid);
        gemm2n_kernel<<<(Hdim / 256) * 32 * Edim, 512, 0, stream>>>(
            hid, w2t, b2, cnt, eoff, ltok, lwp, out2);
        combine_kernel<<<(size_t)Tdim * Hdim / 2048, 256, 0, stream>>>(out2, out);
    } else {
        // round-2 verified fallback
        short* hid = (short*)(wsb + lists_end);
        int CH2 = 2048;
        while (CH2 > 128 && lists_end + (size_t)Edim * CH2 * Ddim * 2 > ws_size) CH2 >>= 1;

        hipMemsetAsync(d_out, 0, (size_t)out_size * 4, stream);
        router_kernel<<<Tdim / 16, 256, 0, stream>>>(x, gw, cnt, psum, ltok, lwp, nullptr);
        aux_kernel<<<1, 64, 0, stream>>>(cnt, psum, eoff, out + (size_t)Tdim * Hdim);

        int chunks = Tdim / CH2;
        for (int c = 0; c < chunks; ++c) {
            gemm1_fb<<<dim3(Ddim / 128, CH2 / 128, Edim), 256, 0, stream>>>(
                x, w1, b1, cnt, ltok, hid, CH2, c * CH2);
            gemm2_fb<<<dim3(Hdim / 128, CH2 / 128, Edim), 256, 0, stream>>>(
                hid, w2, b2, cnt, ltok, lwp, out, CH2, c * CH2);
        }
    }
}

// Round 7
// 337.662 us; speedup vs baseline: 11.6666x; 1.0074x over previous
//
#include <hip/hip_runtime.h>
#include <hip/hip_bf16.h>
#include <math.h>

#define Bdim 2
#define Sdim 4096
#define Hdim 1024
#define Edim 8
#define Ddim 2048
#define Tdim (Bdim*Sdim)   // 8192 tokens

typedef __attribute__((ext_vector_type(8))) __bf16 bfv8;
typedef __attribute__((ext_vector_type(8))) short s16x8;
typedef __attribute__((ext_vector_type(4))) short s16x4;
typedef __attribute__((ext_vector_type(4))) float f32x4;

__device__ __forceinline__ short f2bf(float f) {
    union { float f; unsigned u; } a; a.f = f;
    unsigned r = (a.u + 0x7fffu + ((a.u >> 16) & 1u)) >> 16;
    return (short)r;
}
__device__ __forceinline__ float bf2f(short s) {
    union { unsigned u; float f; } a; a.u = ((unsigned)(unsigned short)s) << 16;
    return a.f;
}
// tanh-form gelu via exp; |err| < 1e-3 abs (below bf16 GEMM noise)
__device__ __forceinline__ float fgelu(float x) {
    float u = fminf(x * (1.5957691f + 0.07135481f * x * x), 60.0f);
    float t = __expf(u);
    return x * t / (t + 1.0f);
}

typedef const __attribute__((address_space(1))) unsigned int ga_u32;
typedef __attribute__((address_space(3))) unsigned int la_u32;

__device__ __forceinline__ void gl_lds16(const void* g, void* l) {
    __builtin_amdgcn_global_load_lds((ga_u32*)g, (la_u32*)l, 16, 0, 0);
}

// counted wait + barrier: certifies oldest loads while keeping N newest in flight
#define WAIT_BAR(N) do {                                     \
    asm volatile("s_waitcnt vmcnt(" #N ")" ::: "memory");    \
    __builtin_amdgcn_s_barrier();                            \
    __builtin_amdgcn_sched_barrier(0);                       \
} while (0)

// ---------------- Router: 512 blocks x 256 thr; wave handles 4 tokens ----------------
// ltok entries encode 2*t + kslot. Also emits xb (bf16 copy of x) when xb != nullptr.
__global__ __launch_bounds__(256) void router_kernel(
    const float* __restrict__ x, const float* __restrict__ gw,
    int* __restrict__ cnt, float* __restrict__ psum,
    int* __restrict__ ltok, float* __restrict__ lw,
    short* __restrict__ xb)
{
    __shared__ float gws[Edim * Hdim];          // 32 KB
    __shared__ int   lcnt[Edim], gbase[Edim];
    __shared__ int   s_e[32], s_pos[32], s_tok[32];
    __shared__ float s_w[32];
    __shared__ float s_ps[4][8];

    int tid = threadIdx.x;
    for (int i = tid; i < Edim * Hdim / 4; i += 256)
        ((float4*)gws)[i] = ((const float4*)gw)[i];
    if (tid < Edim) lcnt[tid] = 0;
    __syncthreads();

    int wave = tid >> 6, lane = tid & 63;
    float ps = 0.f;

    for (int i = 0; i < 4; ++i) {
        int t = blockIdx.x * 16 + wave * 4 + i;
        double acc[Edim];
#pragma unroll
        for (int e = 0; e < Edim; ++e) acc[e] = 0.0;
#pragma unroll
        for (int kq = 0; kq < 4; ++kq) {
            float4 xv = *(const float4*)(x + (size_t)t * Hdim + kq * 256 + lane * 4);
            if (xb) {
                s16x4 h; h[0]=f2bf(xv.x); h[1]=f2bf(xv.y); h[2]=f2bf(xv.z); h[3]=f2bf(xv.w);
                *(s16x4*)(xb + (size_t)t * Hdim + kq * 256 + lane * 4) = h;
            }
#pragma unroll
            for (int e = 0; e < Edim; ++e) {
                float4 wv = *(const float4*)(&gws[e * Hdim + kq * 256 + lane * 4]);
                acc[e] += (double)xv.x * wv.x + (double)xv.y * wv.y
                        + (double)xv.z * wv.z + (double)xv.w * wv.w;
            }
        }
#pragma unroll
        for (int e = 0; e < Edim; ++e) {
            acc[e] += __shfl_xor(acc[e], 1, 64);
            acc[e] += __shfl_xor(acc[e], 2, 64);
            acc[e] += __shfl_xor(acc[e], 4, 64);
        }
        int el = lane & 7;
        double v = acc[0];
#pragma unroll
        for (int e = 1; e < Edim; ++e) if (el == e) v = acc[e];
        v += __shfl_xor(v, 8, 64);
        v += __shfl_xor(v, 16, 64);
        v += __shfl_xor(v, 32, 64);
        double mx = v;
        mx = fmax(mx, __shfl_xor(mx, 1, 64));
        mx = fmax(mx, __shfl_xor(mx, 2, 64));
        mx = fmax(mx, __shfl_xor(mx, 4, 64));
        float ex = __expf((float)(v - mx));
        float sm = ex;
        sm += __shfl_xor(sm, 1, 64);
        sm += __shfl_xor(sm, 2, 64);
        sm += __shfl_xor(sm, 4, 64);
        ps += ex / sm;
        double le[8];
#pragma unroll
        for (int e = 0; e < 8; ++e) le[e] = __shfl(v, e, 8);
        if (lane == 0) {
            int e1 = 0;
#pragma unroll
            for (int e = 1; e < 8; ++e) if (le[e] > le[e1]) e1 = e;
            int e2 = -1;
#pragma unroll
            for (int e = 0; e < 8; ++e) {
                if (e == e1) continue;
                if (e2 < 0 || le[e] > le[e2]) e2 = e;
            }
            float r = __expf((float)(le[e2] - le[e1]));   // p2/p1
            float w1v = 1.0f / (1.0f + r);
            int lt = (wave * 4 + i) * 2;
            int p1 = atomicAdd(&lcnt[e1], 1);
            s_e[lt] = e1; s_pos[lt] = p1; s_tok[lt] = 2*t;     s_w[lt] = w1v;
            int p2 = atomicAdd(&lcnt[e2], 1);
            s_e[lt+1] = e2; s_pos[lt+1] = p2; s_tok[lt+1] = 2*t+1; s_w[lt+1] = 1.0f - w1v;
        }
    }
    if (lane < 8) s_ps[wave][lane] = ps;
    __syncthreads();
    if (tid < 8) {
        atomicAdd(&psum[tid], s_ps[0][tid] + s_ps[1][tid] + s_ps[2][tid] + s_ps[3][tid]);
        gbase[tid] = atomicAdd(&cnt[tid], lcnt[tid]);
    }
    __syncthreads();
    if (tid < 32) {
        int e = s_e[tid];
        int pos = gbase[e] + s_pos[tid];
        ltok[e * Tdim + pos] = s_tok[tid];
        lw[e * Tdim + pos] = s_w[tid];
    }
}

// ---------------- Aux loss + prefix offsets ----------------
__global__ void aux_kernel(const int* __restrict__ cnt,
                           const float* __restrict__ psum,
                           int* __restrict__ eoff,
                           float* __restrict__ out_aux)
{
    if (threadIdx.x == 0 && blockIdx.x == 0) {
        double s = 0.0;
        int run = 0;
        for (int e = 0; e < Edim; ++e) {
            eoff[e] = run;
            run += cnt[e];
            s += ((double)cnt[e] / (double)Bdim) * ((double)psum[e] / (double)Tdim);
        }
        out_aux[0] = (float)((double)Edim * s);
    }
}

// ---------------- Prep: transpose-convert w [E][R][C] fp32 -> wt [E][C][R] bf16 ----------------
__global__ __launch_bounds__(256) void convt_kernel(const float* __restrict__ w,
                                                    short* __restrict__ wt, int R, int C)
{
    int e = blockIdx.z;
    int r0 = blockIdx.y * 64, c0 = blockIdx.x * 64;
    __shared__ short t[64][76];
    int tid = threadIdx.x;
    {
        int r = tid >> 2, cs = (tid & 3) * 16;
        const float* src = w + ((size_t)e * R + r0 + r) * C + c0 + cs;
#pragma unroll
        for (int q = 0; q < 4; ++q) {
            float4 v = *(const float4*)(src + q * 4);
            s16x4 h; h[0]=f2bf(v.x); h[1]=f2bf(v.y); h[2]=f2bf(v.z); h[3]=f2bf(v.w);
            *(s16x4*)(&t[r][cs + q * 4]) = h;
        }
    }
    __syncthreads();
    {
        int c = tid >> 2, rs = (tid & 3) * 16;
        short tmp[16];
#pragma unroll
        for (int j = 0; j < 16; ++j) tmp[j] = t[rs + j][c];
        short* dst = wt + ((size_t)e * C + c0 + c) * R + r0 + rs;
        *(s16x8*)dst = *(s16x8*)tmp;
        *(s16x8*)(dst + 8) = *(s16x8*)(tmp + 8);
    }
}

// ================== 256x256x64, 8 waves, K-half counted-vmcnt pipeline ==================
// LDS (128 KB) per dbuf c in {0,1} (64KB each):
//   [A-Kh0 16K][A-Kh1 16K][B-Kh0 16K][B-Kh1 16K]
// K-half region layout: 2 logical rows (32 shorts each) packed per 128B LDS row,
// XOR-swizzled (bits 4-6 ^ lrow&7) -> ds_read_b128 at free 2-way; gl_lds dest
// linear, source address carries the inverse swizzle (involution).

// ---------------- GEMM1: hid[slot] = gelu(Xb[list] @ w1t^T + b1) -> bf16 ----------------
__global__ __launch_bounds__(512, 2) void gemm1n_kernel(
    const short* __restrict__ xb, const short* __restrict__ w1t,
    const float* __restrict__ b1, const int* __restrict__ cnt,
    const int* __restrict__ eoff, const int* __restrict__ ltok,
    short* __restrict__ hid)
{
    constexpr int GXN = Ddim / 256;  // 8
    int id = blockIdx.x;
    int e = id & 7;
    unsigned rem = (unsigned)id >> 3;
    int bx = rem & (GXN - 1);
    int by = rem / GXN;

    int n_e = cnt[e];
    int row0 = by * 256;
    if (row0 >= n_e) return;
    int col0 = bx * 256;
    int slot0 = eoff[e];

    __shared__ short lds[65536];     // 128 KB
    char* ldsb = (char*)lds;

    int tid = threadIdx.x;
    int w = tid >> 6, lane = tid & 63;

    // staging: 2 chunks per 16KB region per thread; source pre-swizzled
    const short* aS[2]; const short* bS[2];
    int oA[2];
#pragma unroll
    for (int j = 0; j < 2; ++j) {
        int o = tid * 16 + j * 8192;               // dest byte offset in region
        oA[j] = o;
        int eff = o ^ (((o >> 7) & 7) << 4);       // inverse swizzle
        int row = ((eff >> 7) << 1) | ((eff >> 6) & 1);
        int kB  = eff & 63;                        // byte offset within K-half row
        int gr = row0 + row; if (gr > n_e - 1) gr = n_e - 1;
        int tok = ltok[(size_t)e * Tdim + gr] >> 1;
        aS[j] = xb + (size_t)tok * Hdim + (kB >> 1);
        bS[j] = w1t + ((size_t)e * Ddim + col0 + row) * Hdim + (kB >> 1);
    }

    int fr = lane & 15, kg = lane >> 4;
    int wm = (w >> 2) * 128, wn = (w & 3) * 64;

    int offA[8], offB[4];
#pragma unroll
    for (int m = 0; m < 8; ++m) {
        int r = wm + m * 16 + fr;
        offA[m] = (r >> 1) * 64 + ((((r & 1) * 32) + kg * 8) ^ (((r >> 1) & 7) << 3));
    }
#pragma unroll
    for (int n = 0; n < 4; ++n) {
        int r = wn + n * 16 + fr;
        offB[n] = (r >> 1) * 64 + ((((r & 1) * 32) + kg * 8) ^ (((r >> 1) & 7) << 3));
    }

    f32x4 acc[8][4];
#pragma unroll
    for (int m = 0; m < 8; ++m)
#pragma unroll
        for (int n = 0; n < 4; ++n) acc[m][n] = (f32x4)0.0f;

    // stage one K-half (A + B) into region at byte offset dstB; 4 gl_lds/thread
    auto stage = [&](int dstB) {
#pragma unroll
        for (int j = 0; j < 2; ++j) {
            gl_lds16(aS[j], ldsb + dstB + oA[j]);
            gl_lds16(bS[j], ldsb + dstB + 32768 + oA[j]);
            aS[j] += 32; bS[j] += 32;
        }
    };
    // compute one K-half; baseSh = shorts offset of A-Kh region
    auto computeH = [&](int baseSh) {
        bfv8 af[8], bf[4];
#pragma unroll
        for (int n = 0; n < 4; ++n) bf[n] = *(const bfv8*)(lds + baseSh + 16384 + offB[n]);
#pragma unroll
        for (int m = 0; m < 8; ++m) af[m] = *(const bfv8*)(lds + baseSh + offA[m]);
        __builtin_amdgcn_s_setprio(1);
#pragma unroll
        for (int m = 0; m < 8; ++m)
#pragma unroll
            for (int n = 0; n < 4; ++n)
                acc[m][n] = __builtin_amdgcn_mfma_f32_16x16x32_bf16(af[m], bf[n], acc[m][n], 0, 0, 0);
        __builtin_amdgcn_s_setprio(0);
    };

    constexpr int NK = Hdim / 64;    // 16
    // prologue: tile0 -> buf0
    stage(0);                        // t0.Kh0
    stage(16384);                    // t0.Kh1
    for (int k = 0; k < NK - 2; k += 2) {
        // tile k (buf0), stage tile k+1 -> buf1
        stage(65536);         WAIT_BAR(8); computeH(0);
        stage(65536 + 16384); WAIT_BAR(8); computeH(8192);
        // tile k+1 (buf1), stage tile k+2 -> buf0
        stage(0);             WAIT_BAR(8); computeH(32768);
        stage(16384);         WAIT_BAR(8); computeH(40960);
    }
    // final pair: tile NK-2 (buf0) stages NK-1 -> buf1; tile NK-1 tail-counted
    stage(65536);         WAIT_BAR(8); computeH(0);
    stage(65536 + 16384); WAIT_BAR(8); computeH(8192);
    WAIT_BAR(4); computeH(32768);
    WAIT_BAR(0); computeH(40960);

#pragma unroll
    for (int m = 0; m < 8; ++m) {
        int r0r = wm + m * 16 + kg * 4;
#pragma unroll
        for (int j = 0; j < 4; ++j) {
            int gr = row0 + r0r + j;
            if (gr >= n_e) continue;
            size_t hbase = (size_t)(slot0 + gr) * Ddim;
#pragma unroll
            for (int n = 0; n < 4; ++n) {
                int col = col0 + wn + n * 16 + fr;
                float v = acc[m][n][j] + b1[e * Ddim + col];
                hid[hbase + col] = f2bf(fgelu(v));
            }
        }
    }
}

// ---------------- GEMM2: out2[2t+k] = p * (hid @ w2t^T + b2) -> bf16 ----------------
__global__ __launch_bounds__(512, 2) void gemm2n_kernel(
    const short* __restrict__ hid, const short* __restrict__ w2t,
    const float* __restrict__ b2, const int* __restrict__ cnt,
    const int* __restrict__ eoff, const int* __restrict__ ltok,
    const float* __restrict__ lw, short* __restrict__ out2)
{
    constexpr int GXN = Hdim / 256;  // 4
    int id = blockIdx.x;
    int e = id & 7;
    unsigned rem = (unsigned)id >> 3;
    int bx = rem & (GXN - 1);
    int by = rem / GXN;

    int n_e = cnt[e];
    int row0 = by * 256;
    if (row0 >= n_e) return;
    int col0 = bx * 256;
    int slot0 = eoff[e];

    __shared__ short lds[65536];
    char* ldsb = (char*)lds;

    int tid = threadIdx.x;
    int w = tid >> 6, lane = tid & 63;

    const short* aS[2]; const short* bS[2];
    int oA[2];
#pragma unroll
    for (int j = 0; j < 2; ++j) {
        int o = tid * 16 + j * 8192;
        oA[j] = o;
        int eff = o ^ (((o >> 7) & 7) << 4);
        int row = ((eff >> 7) << 1) | ((eff >> 6) & 1);
        int kB  = eff & 63;
        int gr = row0 + row; if (gr > n_e - 1) gr = n_e - 1;
        aS[j] = hid + (size_t)(slot0 + gr) * Ddim + (kB >> 1);
        bS[j] = w2t + ((size_t)e * Hdim + col0 + row) * Ddim + (kB >> 1);
    }

    int fr = lane & 15, kg = lane >> 4;
    int wm = (w >> 2) * 128, wn = (w & 3) * 64;

    int offA[8], offB[4];
#pragma unroll
    for (int m = 0; m < 8; ++m) {
        int r = wm + m * 16 + fr;
        offA[m] = (r >> 1) * 64 + ((((r & 1) * 32) + kg * 8) ^ (((r >> 1) & 7) << 3));
    }
#pragma unroll
    for (int n = 0; n < 4; ++n) {
        int r = wn + n * 16 + fr;
        offB[n] = (r >> 1) * 64 + ((((r & 1) * 32) + kg * 8) ^ (((r >> 1) & 7) << 3));
    }

    f32x4 acc[8][4];
#pragma unroll
    for (int m = 0; m < 8; ++m)
#pragma unroll
        for (int n = 0; n < 4; ++n) acc[m][n] = (f32x4)0.0f;

    auto stage = [&](int dstB) {
#pragma unroll
        for (int j = 0; j < 2; ++j) {
            gl_lds16(aS[j], ldsb + dstB + oA[j]);
            gl_lds16(bS[j], ldsb + dstB + 32768 + oA[j]);
            aS[j] += 32; bS[j] += 32;
        }
    };
    auto computeH = [&](int baseSh) {
        bfv8 af[8], bf[4];
#pragma unroll
        for (int n = 0; n < 4; ++n) bf[n] = *(const bfv8*)(lds + baseSh + 16384 + offB[n]);
#pragma unroll
        for (int m = 0; m < 8; ++m) af[m] = *(const bfv8*)(lds + baseSh + offA[m]);
        __builtin_amdgcn_s_setprio(1);
#pragma unroll
        for (int m = 0; m < 8; ++m)
#pragma unroll
            for (int n = 0; n < 4; ++n)
                acc[m][n] = __builtin_amdgcn_mfma_f32_16x16x32_bf16(af[m], bf[n], acc[m][n], 0, 0, 0);
        __builtin_amdgcn_s_setprio(0);
    };

    constexpr int NK = Ddim / 64;    // 32
    stage(0);
    stage(16384);
    for (int k = 0; k < NK - 2; k += 2) {
        stage(65536);         WAIT_BAR(8); computeH(0);
        stage(65536 + 16384); WAIT_BAR(8); computeH(8192);
        stage(0);             WAIT_BAR(8); computeH(32768);
        stage(16384);         WAIT_BAR(8); computeH(40960);
    }
    stage(65536);         WAIT_BAR(8); computeH(0);
    stage(65536 + 16384); WAIT_BAR(8); computeH(8192);
    WAIT_BAR(4); computeH(32768);
    WAIT_BAR(0); computeH(40960);

#pragma unroll
    for (int m = 0; m < 8; ++m) {
        int r0r = wm + m * 16 + kg * 4;
#pragma unroll
        for (int j = 0; j < 4; ++j) {
            int gr = row0 + r0r + j;
            if (gr >= n_e) continue;
            int val = ltok[(size_t)e * Tdim + gr];
            float p = lw[(size_t)e * Tdim + gr];
            size_t obase = (size_t)val * Hdim;
#pragma unroll
            for (int n = 0; n < 4; ++n) {
                int col = col0 + wn + n * 16 + fr;
                float v = p * (acc[m][n][j] + b2[e * Hdim + col]);
                out2[obase + col] = f2bf(v);
            }
        }
    }
}

// ---------------- Combine: out[t] = out2[2t] + out2[2t+1] ----------------
__global__ __launch_bounds__(256) void combine_kernel(const short* __restrict__ out2,
                                                      float* __restrict__ out)
{
    size_t i = ((size_t)blockIdx.x * 256 + threadIdx.x) * 8;
    size_t t = i >> 10;
    int h = (int)(i & 1023);
    s16x8 a = *(const s16x8*)(out2 + (t * 2) * 1024 + h);
    s16x8 b = *(const s16x8*)(out2 + (t * 2 + 1) * 1024 + h);
#pragma unroll
    for (int j = 0; j < 8; ++j)
        out[i + j] = bf2f(a[j]) + bf2f(b[j]);
}

// ================= Fallback (round-2 verified) kernels =================
#define FBK 64
#define FLDK 72

__global__ __launch_bounds__(256) void gemm1_fb(
    const float* __restrict__ x, const float* __restrict__ w1,
    const float* __restrict__ b1, const int* __restrict__ cnt,
    const int* __restrict__ ltok, short* __restrict__ hid,
    int CH, int row_base)
{
    int e = blockIdx.z;
    int n_e = cnt[e];
    int row0 = row_base + blockIdx.y * 128;
    if (row0 >= n_e) return;
    int col0 = blockIdx.x * 128;

    __shared__ short As[128][FLDK];
    __shared__ short Bs[128][FLDK];

    int tid = threadIdx.x;
    int arow = tid >> 1;
    int akh  = (tid & 1) * 32;
    int gr_a = row0 + arow;
    int tok = ltok[(size_t)e * Tdim + (gr_a < n_e ? gr_a : n_e - 1)] >> 1;
    const float* xrow = x + (size_t)tok * Hdim + akh;
    int bdg = (tid & 31) * 4;
    int bkg = (tid >> 5) * 4;

    int lane = tid & 63;
    int wid = tid >> 6;
    int wm = (wid >> 1) * 64, wn = (wid & 1) * 64;
    int fr = lane & 15, kg = lane >> 4;

    f32x4 acc[4][4];
#pragma unroll
    for (int m = 0; m < 4; ++m)
#pragma unroll
        for (int n = 0; n < 4; ++n) acc[m][n] = (f32x4)0.0f;

    const float* wB = w1 + (size_t)e * Hdim * Ddim + col0;

    for (int k0 = 0; k0 < Hdim; k0 += FBK) {
#pragma unroll
        for (int i = 0; i < 8; ++i) {
            float4 v = *(const float4*)(xrow + k0 + i * 4);
            s16x4 h; h[0] = f2bf(v.x); h[1] = f2bf(v.y); h[2] = f2bf(v.z); h[3] = f2bf(v.w);
            *(s16x4*)(&As[arow][akh + i * 4]) = h;
        }
#pragma unroll
        for (int r = 0; r < 2; ++r) {
            int kq = bkg + r * 32;
            float4 v0 = *(const float4*)(wB + (size_t)(k0 + kq + 0) * Ddim + bdg);
            float4 v1 = *(const float4*)(wB + (size_t)(k0 + kq + 1) * Ddim + bdg);
            float4 v2 = *(const float4*)(wB + (size_t)(k0 + kq + 2) * Ddim + bdg);
            float4 v3 = *(const float4*)(wB + (size_t)(k0 + kq + 3) * Ddim + bdg);
            const float* p0 = (const float*)&v0; const float* p1 = (const float*)&v1;
            const float* p2 = (const float*)&v2; const float* p3 = (const float*)&v3;
#pragma unroll
            for (int c = 0; c < 4; ++c) {
                s16x4 h; h[0] = f2bf(p0[c]); h[1] = f2bf(p1[c]); h[2] = f2bf(p2[c]); h[3] = f2bf(p3[c]);
                *(s16x4*)(&Bs[bdg + c][kq]) = h;
            }
        }
        __syncthreads();
        bfv8 af[4][2], bfr[4][2];
#pragma unroll
        for (int m = 0; m < 4; ++m)
#pragma unroll
            for (int kk = 0; kk < 2; ++kk)
                af[m][kk] = *(const bfv8*)(&As[wm + m * 16 + fr][kk * 32 + kg * 8]);
#pragma unroll
        for (int n = 0; n < 4; ++n)
#pragma unroll
            for (int kk = 0; kk < 2; ++kk)
                bfr[n][kk] = *(const bfv8*)(&Bs[wn + n * 16 + fr][kk * 32 + kg * 8]);
#pragma unroll
        for (int m = 0; m < 4; ++m)
#pragma unroll
            for (int n = 0; n < 4; ++n) {
                acc[m][n] = __builtin_amdgcn_mfma_f32_16x16x32_bf16(af[m][0], bfr[n][0], acc[m][n], 0, 0, 0);
                acc[m][n] = __builtin_amdgcn_mfma_f32_16x16x32_bf16(af[m][1], bfr[n][1], acc[m][n], 0, 0, 0);
            }
        __syncthreads();
    }

    int lr0 = row0 - row_base;
#pragma unroll
    for (int m = 0; m < 4; ++m) {
        int r0r = wm + m * 16 + kg * 4;
#pragma unroll
        for (int j = 0; j < 4; ++j) {
            int gr = row0 + r0r + j;
            if (gr >= n_e) continue;
            size_t hbase = ((size_t)e * CH + (size_t)(lr0 + r0r + j)) * Ddim;
#pragma unroll
            for (int n = 0; n < 4; ++n) {
                int col = col0 + wn + n * 16 + fr;
                float v = acc[m][n][j] + b1[e * Ddim + col];
                float g = 0.5f * v * (1.0f + erff(v * 0.70710678118654752440f));
                hid[hbase + col] = f2bf(g);
            }
        }
    }
}

__global__ __launch_bounds__(256) void gemm2_fb(
    const short* __restrict__ hid, const float* __restrict__ w2,
    const float* __restrict__ b2, const int* __restrict__ cnt,
    const int* __restrict__ ltok, const float* __restrict__ lw,
    float* __restrict__ out, int CH, int row_base)
{
    int e = blockIdx.z;
    int n_e = cnt[e];
    int row0 = row_base + blockIdx.y * 128;
    if (row0 >= n_e) return;
    int col0 = blockIdx.x * 128;

    __shared__ short As[128][FLDK];
    __shared__ short Bs[128][FLDK];

    int tid = threadIdx.x;
    int arow = tid >> 1;
    int akh  = (tid & 1) * 32;
    const short* hrow = hid + ((size_t)e * CH + (size_t)(row0 - row_base + arow)) * Ddim + akh;
    int bdg = (tid & 31) * 4;
    int bkg = (tid >> 5) * 4;

    int lane = tid & 63;
    int wid = tid >> 6;
    int wm = (wid >> 1) * 64, wn = (wid & 1) * 64;
    int fr = lane & 15, kg = lane >> 4;

    f32x4 acc[4][4];
#pragma unroll
    for (int m = 0; m < 4; ++m)
#pragma unroll
        for (int n = 0; n < 4; ++n) acc[m][n] = (f32x4)0.0f;

    const float* wB = w2 + (size_t)e * Ddim * Hdim + col0;

    for (int k0 = 0; k0 < Ddim; k0 += FBK) {
#pragma unroll
        for (int i = 0; i < 4; ++i) {
            s16x8 v = *(const s16x8*)(hrow + k0 + i * 8);
            *(s16x8*)(&As[arow][akh + i * 8]) = v;
        }
#pragma unroll
        for (int r = 0; r < 2; ++r) {
            int kq = bkg + r * 32;
            float4 v0 = *(const float4*)(wB + (size_t)(k0 + kq + 0) * Hdim + bdg);
            float4 v1 = *(const float4*)(wB + (size_t)(k0 + kq + 1) * Hdim + bdg);
            float4 v2 = *(const float4*)(wB + (size_t)(k0 + kq + 2) * Hdim + bdg);
            float4 v3 = *(const float4*)(wB + (size_t)(k0 + kq + 3) * Hdim + bdg);
            const float* p0 = (const float*)&v0; const float* p1 = (const float*)&v1;
            const float* p2 = (const float*)&v2; const float* p3 = (const float*)&v3;
#pragma unroll
            for (int c = 0; c < 4; ++c) {
                s16x4 h; h[0] = f2bf(p0[c]); h[1] = f2bf(p1[c]); h[2] = f2bf(p2[c]); h[3] = f2bf(p3[c]);
                *(s16x4*)(&Bs[bdg + c][kq]) = h;
            }
        }
        __syncthreads();
        bfv8 af[4][2], bfr[4][2];
#pragma unroll
        for (int m = 0; m < 4; ++m)
#pragma unroll
            for (int kk = 0; kk < 2; ++kk)
                af[m][kk] = *(const bfv8*)(&As[wm + m * 16 + fr][kk * 32 + kg * 8]);
#pragma unroll
        for (int n = 0; n < 4; ++n)
#pragma unroll
            for (int kk = 0; kk < 2; ++kk)
                bfr[n][kk] = *(const bfv8*)(&Bs[wn + n * 16 + fr][kk * 32 + kg * 8]);
#pragma unroll
        for (int m = 0; m < 4; ++m)
#pragma unroll
            for (int n = 0; n < 4; ++n) {
                acc[m][n] = __builtin_amdgcn_mfma_f32_16x16x32_bf16(af[m][0], bfr[n][0], acc[m][n], 0, 0, 0);
                acc[m][n] = __builtin_amdgcn_mfma_f32_16x16x32_bf16(af[m][1], bfr[n][1], acc[m][n], 0, 0, 0);
            }
        __syncthreads();
    }

#pragma unroll
    for (int m = 0; m < 4; ++m) {
        int r0r = wm + m * 16 + kg * 4;
#pragma unroll
        for (int j = 0; j < 4; ++j) {
            int gr = row0 + r0r + j;
            if (gr >= n_e) continue;
            int tok = ltok[(size_t)e * Tdim + gr] >> 1;
            float p = lw[(size_t)e * Tdim + gr];
#pragma unroll
            for (int n = 0; n < 4; ++n) {
                int col = col0 + wn + n * 16 + fr;
                float v = p * (acc[m][n][j] + b2[e * Hdim + col]);
                atomicAdd(&out[(size_t)tok * Hdim + col], v);
            }
        }
    }
}

// ---------------- Host launch ----------------
extern "C" void kernel_launch(void* const* d_in, const int* in_sizes, int n_in,
                              void* d_out, int out_size, void* d_ws, size_t ws_size,
                              hipStream_t stream)
{
    const float* x  = (const float*)d_in[0];
    const float* gw = (const float*)d_in[1];
    const float* w1 = (const float*)d_in[2];
    const float* b1 = (const float*)d_in[3];
    const float* w2 = (const float*)d_in[4];
    const float* b2 = (const float*)d_in[5];
    float* out = (float*)d_out;

    char* wsb = (char*)d_ws;
    // hdr: cnt[8]@0, psum[8]@32, eoff[8]@64, pad to 128
    int*   cnt  = (int*)wsb;
    float* psum = (float*)(wsb + 32);
    int*   eoff = (int*)(wsb + 64);
    int*   ltok = (int*)(wsb + 128);
    float* lwp  = (float*)(wsb + 128 + (size_t)Edim * Tdim * 4);
    size_t lists_end = 128 + (size_t)Edim * Tdim * 8;

    size_t xb_sz = (size_t)Tdim * Hdim * 2;          // 16 MB
    size_t w1t_sz = (size_t)Edim * Hdim * Ddim * 2;  // 32 MB
    size_t w2t_sz = w1t_sz;                          // 32 MB
    size_t hid_sz = (size_t)(2 * Tdim) * Ddim * 2;   // 64 MB (slot-compact)
    size_t req = lists_end + xb_sz + w1t_sz + w2t_sz + hid_sz;

    hipMemsetAsync(wsb, 0, 128, stream);

    if (req <= ws_size) {
        short* xb   = (short*)(wsb + lists_end);
        short* w1t  = (short*)(wsb + lists_end + xb_sz);
        short* w2t  = (short*)(wsb + lists_end + xb_sz + w1t_sz);
        short* hid  = (short*)(wsb + lists_end + xb_sz + w1t_sz + w2t_sz);
        short* out2 = w1t;   // alias: w1t dead once all gemm1n blocks finish

        convt_kernel<<<dim3(Ddim / 64, Hdim / 64, Edim), 256, 0, stream>>>(w1, w1t, Hdim, Ddim);
        convt_kernel<<<dim3(Hdim / 64, Ddim / 64, Edim), 256, 0, stream>>>(w2, w2t, Ddim, Hdim);
        router_kernel<<<Tdim / 16, 256, 0, stream>>>(x, gw, cnt, psum, ltok, lwp, xb);
        aux_kernel<<<1, 64, 0, stream>>>(cnt, psum, eoff, out + (size_t)Tdim * Hdim);

        gemm1n_kernel<<<(Ddim / 256) * 32 * Edim, 512, 0, stream>>>(
            xb, w1t, b1, cnt, eoff, ltok, hid);
        gemm2n_kernel<<<(Hdim / 256) * 32 * Edim, 512, 0, stream>>>(
            hid, w2t, b2, cnt, eoff, ltok, lwp, out2);
        combine_kernel<<<(size_t)Tdim * Hdim / 2048, 256, 0, stream>>>(out2, out);
    } else {
        // round-2 verified fallback
        short* hid = (short*)(wsb + lists_end);
        int CH2 = 2048;
        while (CH2 > 128 && lists_end + (size_t)Edim * CH2 * Ddim * 2 > ws_size) CH2 >>= 1;

        hipMemsetAsync(d_out, 0, (size_t)out_size * 4, stream);
        router_kernel<<<Tdim / 16, 256, 0, stream>>>(x, gw, cnt, psum, ltok, lwp, nullptr);
        aux_kernel<<<1, 64, 0, stream>>>(cnt, psum, eoff, out + (size_t)Tdim * Hdim);

        int chunks = Tdim / CH2;
        for (int c = 0; c < chunks; ++c) {
            gemm1_fb<<<dim3(Ddim / 128, CH2 / 128, Edim), 256, 0, stream>>>(
                x, w1, b1, cnt, ltok, hid, CH2, c * CH2);
            gemm2_fb<<<dim3(Hdim / 128, CH2 / 128, Edim), 256, 0, stream>>>(
                hid, w2, b2, cnt, ltok, lwp, out, CH2, c * CH2);
        }
    }
}